// Round 2
// baseline (302601.880 us; speedup 1.0000x reference)
//
#include <hip/hip_runtime.h>

#define T_LEN 512
#define BATCH 64
#define FEATD 512
#define HID   1024
#define G4H   4096
#define WINR  16
#define WLEN  33
#define OUTD  512
#define CATD  1536
#define NBLK  256
#define NTHR  512

typedef unsigned int uint32;
typedef unsigned short ushort16;
typedef short s16x8 __attribute__((ext_vector_type(8)));
typedef float f32x4 __attribute__((ext_vector_type(4)));

// ---------------- workspace layout (float offsets) ----------------
// u:      [T][B][H] fp32                33,554,432
// hhT:    [3][4H][B] fp32                  786,432
// s:      [B][H] fp32                       65,536
// (retired cB4 region)                      16,384
// x1B4:   [H/4][64][4] bf16   65536 sh ->   32,768
// x2B4:   [H/4][64][4] bf16   65536 sh ->   32,768
// chist4: [16][F/4][64][4] bf16 524288 sh -> 262,144
// xhist4: [16][H/4][64][4] bf16 1048576 sh-> 524,288
// bar:    1024 u32                           1,024
// Wfcb:   [32 ot][48 ks][64][8] bf16 786432 sh -> 393,216
// total ~35.67M floats = 142.7 MB
static const size_t OFF_U    = 0;
static const size_t OFF_HH   = 33554432;
static const size_t OFF_S    = OFF_HH + 786432;
static const size_t OFF_CB   = OFF_S  + 65536;
static const size_t OFF_X1   = OFF_CB + 16384;
static const size_t OFF_X2   = OFF_X1 + 32768;
static const size_t OFF_CK   = OFF_X2 + 32768;
static const size_t OFF_XK   = OFF_CK + 262144;
static const size_t OFF_BAR  = OFF_XK + 524288;
static const size_t OFF_WFCB = OFF_BAR + 1024;

__device__ __forceinline__ float sigmoidf_(float x) { return 1.0f / (1.0f + expf(-x)); }
__device__ __forceinline__ ushort16 f2bf(float f) {
  uint32 u = __float_as_uint(f);
  uint32 r = u + 0x7FFFu + ((u >> 16) & 1u);   // RNE
  return (ushort16)(r >> 16);
}
__device__ __forceinline__ float bf2f(ushort16 u) {
  return __uint_as_float(((uint32)u) << 16);
}

// ---------------- two-level grid barrier (256 blocks) ----------------
__device__ __forceinline__ void grid_barrier(unsigned* bar) {
  __syncthreads();
  __threadfence();
  if (threadIdx.x == 0) {
    unsigned* cnt  = bar + ((blockIdx.x & 7u) << 6);
    unsigned* gcnt = bar + 512;
    unsigned* gen  = bar + 576;
    unsigned g = __hip_atomic_load(gen, __ATOMIC_ACQUIRE, __HIP_MEMORY_SCOPE_AGENT);
    unsigned a = __hip_atomic_fetch_add(cnt, 1u, __ATOMIC_ACQ_REL, __HIP_MEMORY_SCOPE_AGENT);
    if (a == 31u) {
      __hip_atomic_store(cnt, 0u, __ATOMIC_RELAXED, __HIP_MEMORY_SCOPE_AGENT);
      unsigned ga = __hip_atomic_fetch_add(gcnt, 1u, __ATOMIC_ACQ_REL, __HIP_MEMORY_SCOPE_AGENT);
      if (ga == 7u) {
        __hip_atomic_store(gcnt, 0u, __ATOMIC_RELAXED, __HIP_MEMORY_SCOPE_AGENT);
        __hip_atomic_fetch_add(gen, 1u, __ATOMIC_ACQ_REL, __HIP_MEMORY_SCOPE_AGENT);
      } else {
        while (__hip_atomic_load(gen, __ATOMIC_RELAXED, __HIP_MEMORY_SCOPE_AGENT) == g)
          __builtin_amdgcn_s_sleep(1);
      }
    } else {
      while (__hip_atomic_load(gen, __ATOMIC_RELAXED, __HIP_MEMORY_SCOPE_AGENT) == g)
        __builtin_amdgcn_s_sleep(1);
    }
  }
  __syncthreads();
  __threadfence();
}

// ---------------- MFMA LSTM stage ----------------
// Block owns 16 W-rows: m = gate*4 + jl, row n = gate*HID + blockIdx*4 + jl.
// A-frags (bf16) pre-swizzled in LDS: wl[ks][lane][8], k = ks*32 + quad*8 + j.
// B-frags from global actB4 [K/4][64][4] bf16 (b-major groups of 4 k).
// Waves: nt = wv&3 (N-tile of 16 b), kh = wv>>2 (K-half). LDS-reduce, gate math.
// Dual accumulator chains halve the dependent-MFMA latency.
template<int KSTEPS>
__device__ __forceinline__ void lstm_stage_mfma(
    const ushort16* __restrict__ wl,     // LDS [KSTEPS][64][8]
    const ushort16* __restrict__ actB4,  // global [K/4][64][4]
    const float* __restrict__ hhT,       // [4H][64] (this layer)
    const float* __restrict__ c0l,       // [B][HID] b-major (this layer)
    ushort16* __restrict__ xoutB4,       // next act [H/4][64][4] or null
    ushort16* __restrict__ xhist_slot,   // [H/4][64][4] or null
    float* __restrict__ sOut,            // [B][HID] or null
    float* __restrict__ red)             // LDS [2][4][16][16]
{
  const int tid  = threadIdx.x;
  const int wv   = tid >> 6;
  const int lane = tid & 63;
  const int nt   = wv & 3;
  const int kh   = wv >> 2;
  const int quad = lane >> 4;
  const int b    = nt * 16 + (lane & 15);
  const int half = KSTEPS / 2;

  f32x4 acc0 = {0.f, 0.f, 0.f, 0.f};
  f32x4 acc1 = {0.f, 0.f, 0.f, 0.f};
  #pragma unroll 4
  for (int i = 0; i < half; i += 2) {
    const int ks0 = kh * half + i;
    const int ks1 = ks0 + 1;
    s16x8 a0 = *(const s16x8*)(wl + ((size_t)ks0 * 64 + lane) * 8);
    s16x8 a1 = *(const s16x8*)(wl + ((size_t)ks1 * 64 + lane) * 8);
    const int g0 = ks0 * 8 + quad * 2;
    const int g1 = ks1 * 8 + quad * 2;
    uint2 lo0 = *(const uint2*)(actB4 + ((size_t)g0 * 64 + b) * 4);
    uint2 hi0 = *(const uint2*)(actB4 + ((size_t)(g0 + 1) * 64 + b) * 4);
    uint2 lo1 = *(const uint2*)(actB4 + ((size_t)g1 * 64 + b) * 4);
    uint2 hi1 = *(const uint2*)(actB4 + ((size_t)(g1 + 1) * 64 + b) * 4);
    union { uint4 u; s16x8 v; } b0, b1;
    b0.u = make_uint4(lo0.x, lo0.y, hi0.x, hi0.y);
    b1.u = make_uint4(lo1.x, lo1.y, hi1.x, hi1.y);
    acc0 = __builtin_amdgcn_mfma_f32_16x16x32_bf16(a0, b0.v, acc0, 0, 0, 0);
    acc1 = __builtin_amdgcn_mfma_f32_16x16x32_bf16(a1, b1.v, acc1, 0, 0, 0);
  }
  f32x4 acc = acc0 + acc1;
  // partials: C-layout col=lane&15, row=quad*4+reg
  {
    float* rp = red + (((size_t)(kh * 4 + nt) * 16 + quad * 4) * 16) + (lane & 15);
    rp[0]  = acc[0];
    rp[16] = acc[1];
    rp[32] = acc[2];
    rp[48] = acc[3];
  }
  __syncthreads();
  if (wv < 4) {
    const int jl = wv;
    const int bb = lane;
    const int ntb = bb >> 4, col = bb & 15;
    const int j = (blockIdx.x << 2) + jl;
    float g[4];
    #pragma unroll
    for (int gate = 0; gate < 4; ++gate) {
      const int m = gate * 4 + jl;
      g[gate] = red[((size_t)(0 + ntb) * 16 + m) * 16 + col]
              + red[((size_t)(4 + ntb) * 16 + m) * 16 + col]
              + hhT[((size_t)gate * HID + j) * 64 + bb];
    }
    float cn = sigmoidf_(g[1]) * c0l[(size_t)bb * HID + j] + sigmoidf_(g[0]) * tanhf(g[2]);
    float hv = sigmoidf_(g[3]) * tanhf(cn);
    ushort16 hb = f2bf(hv);
    if (xoutB4)     xoutB4[((size_t)blockIdx.x * 64 + bb) * 4 + jl] = hb;   // group j>>2 == blockIdx
    if (xhist_slot) xhist_slot[((size_t)blockIdx.x * 64 + bb) * 4 + jl] = hb; // B4 layout for FC MFMA
    if (sOut)       sOut[(size_t)bb * HID + j] = hv;                        // scatter (small)
  }
}

// ---------------- FC head on the MFMA pipe ----------------
// Per tp: out[b][o] = relu(Wfc[o,:1536] . [x;c][:,b] + bfc[o]).
// 64 blocks/tp. Block sub: ot = sub>>1 (16 o's), b-half = sub&1 (32 b's).
// 8 waves: wv&1 -> b-tile within half, wv>>1 -> K-quarter (12 ksteps of 32).
// A-frags from pre-swizzled bf16 Wfcb [ot][ks][lane][8] (same lane->(m,k)
// convention as the LSTM wlds). B-frags from B4-layout hist slots.
__device__ __forceinline__ void fc_step_mfma(int tp, int sub,
    const ushort16* __restrict__ ch4,   // [16][F/4][64][4]
    const ushort16* __restrict__ xh4,   // [16][H/4][64][4]
    const ushort16* __restrict__ Wfcb,  // [32][48][64][8]
    const float* __restrict__ bfc,
    float* __restrict__ outp, float* __restrict__ red)
{
  const int tid  = threadIdx.x;
  const int wv   = tid >> 6;
  const int lane = tid & 63;
  const int slot = tp & 15;
  const int ot   = sub >> 1;                 // 0..31
  const int tsel = wv & 1;                   // b-tile within half
  const int kq   = wv >> 1;                  // 0..3 K-quarter
  const int quad = lane >> 4;
  const int b    = ((sub & 1) * 2 + tsel) * 16 + (lane & 15);
  const ushort16* xs = xh4 + (size_t)slot * 65536;   // [256][64][4]
  const ushort16* cs = ch4 + (size_t)slot * 32768;   // [128][64][4]
  const ushort16* wa = Wfcb + ((size_t)ot * 48 + (size_t)kq * 12) * 512;

  f32x4 acc0 = {0.f, 0.f, 0.f, 0.f};
  f32x4 acc1 = {0.f, 0.f, 0.f, 0.f};
  #pragma unroll
  for (int i = 0; i < 12; i += 2) {
    const int ks0 = kq * 12 + i;
    const int ks1 = ks0 + 1;
    s16x8 a0 = *(const s16x8*)(wa + (size_t)i * 512 + (size_t)lane * 8);
    s16x8 a1 = *(const s16x8*)(wa + (size_t)(i + 1) * 512 + (size_t)lane * 8);
    const ushort16* s0p = (ks0 < 32) ? xs : cs;
    const ushort16* s1p = (ks1 < 32) ? xs : cs;
    const int gg0 = ((ks0 < 32) ? ks0 * 8 : (ks0 - 32) * 8) + quad * 2;
    const int gg1 = ((ks1 < 32) ? ks1 * 8 : (ks1 - 32) * 8) + quad * 2;
    uint2 lo0 = *(const uint2*)(s0p + ((size_t)gg0 * 64 + b) * 4);
    uint2 hi0 = *(const uint2*)(s0p + ((size_t)(gg0 + 1) * 64 + b) * 4);
    uint2 lo1 = *(const uint2*)(s1p + ((size_t)gg1 * 64 + b) * 4);
    uint2 hi1 = *(const uint2*)(s1p + ((size_t)(gg1 + 1) * 64 + b) * 4);
    union { uint4 u; s16x8 v; } b0, b1;
    b0.u = make_uint4(lo0.x, lo0.y, hi0.x, hi0.y);
    b1.u = make_uint4(lo1.x, lo1.y, hi1.x, hi1.y);
    acc0 = __builtin_amdgcn_mfma_f32_16x16x32_bf16(a0, b0.v, acc0, 0, 0, 0);
    acc1 = __builtin_amdgcn_mfma_f32_16x16x32_bf16(a1, b1.v, acc1, 0, 0, 0);
  }
  f32x4 acc = acc0 + acc1;
  // partials: red[wv][row=quad*4+r][col=lane&15], wv = kq*2 + tsel
  {
    float* rp = red + ((size_t)wv * 16 + quad * 4) * 16 + (lane & 15);
    rp[0]  = acc[0];
    rp[16] = acc[1];
    rp[32] = acc[2];
    rp[48] = acc[3];
  }
  __syncthreads();
  // reduce 4 K-quarters + bias + relu. tid = tl*256 + bcol*16 + m (o fastest
  // so the 16-lane store chunks are 64B contiguous in out).
  {
    const int tl   = tid >> 8;          // b-tile
    const int bcol = (tid >> 4) & 15;
    const int m    = tid & 15;
    float v = bfc[ot * 16 + m];
    #pragma unroll
    for (int k4 = 0; k4 < 4; ++k4)
      v += red[((size_t)(k4 * 2 + tl) * 16 + m) * 16 + bcol];
    const int bo = ((sub & 1) * 2 + tl) * 16 + bcol;
    outp[((size_t)tp * BATCH + bo) * OUTD + ot * 16 + m] = fmaxf(v, 0.f);
  }
}

// ---------------- persistent per-speaker decoder ----------------
__global__ void __launch_bounds__(NTHR)
decoder_kernel(const float* __restrict__ hin, const float* __restrict__ u,
               const float* __restrict__ Wih0, const float* __restrict__ Wihr,
               const ushort16* __restrict__ Wfcb, const float* __restrict__ bfc,
               const float* __restrict__ c0, const float* __restrict__ hhT,
               float* __restrict__ s,
               ushort16* __restrict__ x1B4, ushort16* __restrict__ x2B4,
               ushort16* __restrict__ chist4, ushort16* __restrict__ xhist4,
               unsigned* __restrict__ bar, float* __restrict__ outp)
{
  __shared__ ushort16 wlds[40960];   // 80 KB: B[0,8192) C[8192,24576) D[24576,40960)
  __shared__ float s_l[HID];
  __shared__ float e_l[64];
  __shared__ float a_l[64];
  __shared__ float red[2 * 4 * 16 * 16];

  const int tid  = threadIdx.x;
  const int bid  = blockIdx.x;
  const int wv   = tid >> 6;
  const int lane = tid & 63;

  // ---- one-time: swizzle this block's weight slice into LDS (bf16 A-frags) ----
  for (int r = tid; r < 40960; r += NTHR) {
    int local, ksz; const float* Wsrc;
    if (r < 8192)        { local = r;         ksz = FEATD; Wsrc = Wih0; }
    else if (r < 24576)  { local = r - 8192;  ksz = HID;   Wsrc = Wihr; }
    else                 { local = r - 24576; ksz = HID;   Wsrc = Wihr + (size_t)G4H * HID; }
    const int ks   = local >> 9;
    const int li   = local & 511;
    const int ln   = li >> 3;
    const int jj   = li & 7;
    const int m    = ln & 15;
    const int quad = ln >> 4;
    const int k    = ks * 32 + quad * 8 + jj;
    const int n    = (m >> 2) * HID + (bid << 2) + (m & 3);
    wlds[r] = f2bf(Wsrc[(size_t)n * ksz + k]);
  }
  __syncthreads();

  for (int t = 0; t < T_LEN; ++t) {
    const int slot = t & 15;
    // ---- Stage A: attention (blocks 0..63) / FC bursts (blocks 64..255, every 3rd) ----
    if (bid < BATCH) {
      const int b = bid;
      s_l[tid]        = s[(size_t)b * HID + tid];
      s_l[tid + NTHR] = s[(size_t)b * HID + tid + NTHR];
      __syncthreads();
      for (int w = wv; w < WLEN; w += 8) {
        const int tau = t + w - WINR;
        float e = 0.f;   // zero-padded window -> e=0 participates in softmax
        if (tau >= 0 && tau < T_LEN) {
          const float* up = u + ((size_t)tau * BATCH + b) * HID;
          #pragma unroll
          for (int i = 0; i < 16; ++i) {
            const int hidx = lane + (i << 6);
            e += s_l[hidx] * up[hidx];
          }
          #pragma unroll
          for (int m = 32; m; m >>= 1) e += __shfl_xor(e, m);
        }
        if (lane == 0) e_l[w] = e;
      }
      __syncthreads();
      if (tid < 64) {
        float e = (tid < WLEN) ? e_l[tid] : -1e30f;
        float mx = e;
        #pragma unroll
        for (int m = 32; m; m >>= 1) mx = fmaxf(mx, __shfl_xor(mx, m));
        float p = (tid < WLEN) ? expf(e - mx) : 0.f;
        float sm = p;
        #pragma unroll
        for (int m = 32; m; m >>= 1) sm += __shfl_xor(sm, m);
        if (tid < WLEN) a_l[tid] = p / sm;
      }
      __syncthreads();
      {
        // context: branch-free bounds + dual FMA chains
        const int w0 = (t < WINR) ? (WINR - t) : 0;
        const int w1 = (T_LEN + WINR - t < WLEN) ? (T_LEN + WINR - t) : WLEN;
        const size_t hstep = (size_t)BATCH * FEATD;
        const float* hp = hin + ((size_t)(t + w0 - WINR) * BATCH + b) * FEATD + tid;
        float ca = 0.f, cb = 0.f;
        int w = w0;
        for (; w + 1 < w1; w += 2) {
          ca = fmaf(a_l[w],     hp[0],     ca);
          cb = fmaf(a_l[w + 1], hp[hstep], cb);
          hp += 2 * hstep;
        }
        if (w < w1) ca = fmaf(a_l[w], hp[0], ca);
        // write context straight into this step's chist slot (B4/MFMA layout);
        // stage B consumes it directly, FC consumes it 3..5 steps later.
        chist4[(size_t)slot * 32768 + ((size_t)(tid >> 2) * 64 + b) * 4 + (tid & 3)] = f2bf(ca + cb);
      }
    } else if (t >= 3 && t % 3 == 0) {
      const int fb = bid - BATCH;           // 0..191
      const int tp = t - 3 + (fb >> 6);     // 3 timesteps x 64 blocks
      fc_step_mfma(tp, fb & 63, chist4, xhist4, Wfcb, bfc, outp, red);
    }
    grid_barrier(bar);
    // ---- Stages B/C/D ----
    lstm_stage_mfma<16>(wlds, chist4 + (size_t)slot * 32768, hhT, c0,
                        x1B4, nullptr, nullptr, red);
    grid_barrier(bar);
    lstm_stage_mfma<32>(wlds + 8192, x1B4, hhT + (size_t)G4H * 64,
                        c0 + (size_t)BATCH * HID, x2B4, nullptr, nullptr, red);
    grid_barrier(bar);
    lstm_stage_mfma<32>(wlds + 24576, x2B4, hhT + (size_t)2 * G4H * 64,
                        c0 + (size_t)2 * BATCH * HID, nullptr,
                        xhist4 + (size_t)slot * 65536, s, red);
    grid_barrier(bar);
  }
  // ---- epilogue: FC for tp = 510, 511 on blocks 0..127 ----
  if (bid < 128) {
    const int tp = 510 + (bid >> 6);
    fc_step_mfma(tp, bid & 63, chist4, xhist4, Wfcb, bfc, outp, red);
  }
}

// ---------------- one-time: swizzle Wfc into bf16 MFMA A-frags ----------------
// Wfcb[((ot*48 + ks)*64 + ln)*8 + j] = bf16(Wfc[ot*16 + (ln&15)][ks*32 + (ln>>4)*8 + j])
__global__ void __launch_bounds__(256)
wfcswz_kernel(const float* __restrict__ Wfc, ushort16* __restrict__ Wfcb)
{
  const int idx = blockIdx.x * 256 + threadIdx.x;   // 786432 total
  const int ot  = idx / 24576;
  const int r   = idx - ot * 24576;
  const int ks  = r >> 9;
  const int li  = r & 511;
  const int ln  = li >> 3;
  const int j   = li & 7;
  const int k   = ks * 32 + (ln >> 4) * 8 + j;
  const int o   = ot * 16 + (ln & 15);
  Wfcb[idx] = f2bf(Wfc[(size_t)o * CATD + k]);
}

// ---------------- u = h @ Wa_sp^T : [32768,512] x [1024,512]^T (fp32) ----------------
__global__ void __launch_bounds__(256)
gemm_u_kernel(const float* __restrict__ A, const float* __restrict__ Bm,
              float* __restrict__ C)
{
  __shared__ float Al[64 * 68];
  __shared__ float Bl[64 * 68];
  const int tid = threadIdx.x;
  const int m0 = blockIdx.x * 64;
  const int n0 = blockIdx.y * 64;
  const int tx = tid & 15, ty = tid >> 4;
  float acc[4][4] = {};
  for (int kc = 0; kc < 512; kc += 64) {
    #pragma unroll
    for (int p = 0; p < 4; ++p) {
      const int row = p * 16 + (tid >> 4);
      const int kq  = (tid & 15) * 4;
      float4 v = *(const float4*)(A + (size_t)(m0 + row) * 512 + kc + kq);
      Al[(kq + 0) * 68 + row] = v.x;
      Al[(kq + 1) * 68 + row] = v.y;
      Al[(kq + 2) * 68 + row] = v.z;
      Al[(kq + 3) * 68 + row] = v.w;
      float4 w = *(const float4*)(Bm + (size_t)(n0 + row) * 512 + kc + kq);
      Bl[(kq + 0) * 68 + row] = w.x;
      Bl[(kq + 1) * 68 + row] = w.y;
      Bl[(kq + 2) * 68 + row] = w.z;
      Bl[(kq + 3) * 68 + row] = w.w;
    }
    __syncthreads();
    #pragma unroll 8
    for (int k = 0; k < 64; ++k) {
      float4 av = *(const float4*)(&Al[k * 68 + ty * 4]);
      float4 bv = *(const float4*)(&Bl[k * 68 + tx * 4]);
      float aa[4] = {av.x, av.y, av.z, av.w};
      float bb[4] = {bv.x, bv.y, bv.z, bv.w};
      #pragma unroll
      for (int i = 0; i < 4; ++i)
        #pragma unroll
        for (int jj = 0; jj < 4; ++jj)
          acc[i][jj] = fmaf(aa[i], bb[jj], acc[i][jj]);
    }
    __syncthreads();
  }
  #pragma unroll
  for (int i = 0; i < 4; ++i) {
    float4 r = {acc[i][0], acc[i][1], acc[i][2], acc[i][3]};
    *(float4*)(C + (size_t)(m0 + ty * 4 + i) * 1024 + n0 + tx * 4) = r;
  }
}

// ------- hhT[l][n][b] = h0[l,b,:] . Whh_l[n,:] + bih_l[n] + bhh_l[n] -------
__global__ void __launch_bounds__(256)
hhconst_kernel(const float* __restrict__ Whh0, const float* __restrict__ Whr,
               const float* __restrict__ bih0, const float* __restrict__ bhh0,
               const float* __restrict__ bihr, const float* __restrict__ bhhr,
               const float* __restrict__ h0, float* __restrict__ hh)
{
  const int idx = blockIdx.x * 256 + threadIdx.x;   // 786432 total
  const int b = idx & 63;
  const int n = (idx >> 6) & 4095;
  const int l = idx >> 18;
  const float* W = (l == 0) ? (Whh0 + (size_t)n * HID)
                            : (Whr + ((size_t)(l - 1) * G4H + n) * HID);
  float acc = ((l == 0) ? bih0[n] : bihr[(l - 1) * G4H + n])
            + ((l == 0) ? bhh0[n] : bhhr[(l - 1) * G4H + n]);
  const float* hr = h0 + ((size_t)l * BATCH + b) * HID;
  #pragma unroll 2
  for (int k = 0; k < HID; k += 4) {
    float4 a4 = *(const float4*)(hr + k);
    float4 w4 = *(const float4*)(W + k);
    acc += a4.x * w4.x + a4.y * w4.y + a4.z * w4.z + a4.w * w4.w;
  }
  hh[idx] = acc;    // (l*G4H + n)*64 + b  -> k-major, coalesced
}

__global__ void __launch_bounds__(256)
init_kernel(const float* __restrict__ s0, float* __restrict__ s, unsigned* __restrict__ bar)
{
  const int gid = blockIdx.x * 256 + threadIdx.x;
  if (gid < BATCH * HID) s[gid] = s0[gid];
  if (blockIdx.x == 0)
    for (int i = threadIdx.x; i < 1024; i += 256) bar[i] = 0u;
}

extern "C" void kernel_launch(void* const* d_in, const int* in_sizes, int n_in,
                              void* d_out, int out_size, void* d_ws, size_t ws_size,
                              hipStream_t stream) {
  (void)in_sizes; (void)n_in; (void)out_size; (void)ws_size;
  const float* h    = (const float*)d_in[0];
  const float* Wa   = (const float*)d_in[1];
  const float* Wih0 = (const float*)d_in[2];
  const float* Whh0 = (const float*)d_in[3];
  const float* bih0 = (const float*)d_in[4];
  const float* bhh0 = (const float*)d_in[5];
  const float* Wihr = (const float*)d_in[6];
  const float* Whhr = (const float*)d_in[7];
  const float* bihr = (const float*)d_in[8];
  const float* bhhr = (const float*)d_in[9];
  const float* Wfc  = (const float*)d_in[10];
  const float* bfc  = (const float*)d_in[11];
  const float* s0   = (const float*)d_in[12];
  const float* h0   = (const float*)d_in[13];
  const float* c0   = (const float*)d_in[14];
  float* out = (float*)d_out;
  float* ws  = (float*)d_ws;

  float* u         = ws + OFF_U;
  float* hhT       = ws + OFF_HH;
  float* s         = ws + OFF_S;
  ushort16* x1B4   = (ushort16*)(ws + OFF_X1);
  ushort16* x2B4   = (ushort16*)(ws + OFF_X2);
  ushort16* chist4 = (ushort16*)(ws + OFF_CK);
  ushort16* xhist4 = (ushort16*)(ws + OFF_XK);
  unsigned* bar    = (unsigned*)(ws + OFF_BAR);
  ushort16* Wfcb   = (ushort16*)(ws + OFF_WFCB);

  hipLaunchKernelGGL(init_kernel, dim3(256), dim3(256), 0, stream, s0, s, bar);
  hipLaunchKernelGGL(hhconst_kernel, dim3(3072), dim3(256), 0, stream,
                     Whh0, Whhr, bih0, bhh0, bihr, bhhr, h0, hhT);
  hipLaunchKernelGGL(wfcswz_kernel, dim3(3072), dim3(256), 0, stream, Wfc, Wfcb);
  for (int sp = 0; sp < 2; ++sp) {
    hipLaunchKernelGGL(gemm_u_kernel, dim3(512, 16), dim3(256), 0, stream,
                       h, Wa + (size_t)sp * HID * FEATD, u);
    hipLaunchKernelGGL(decoder_kernel, dim3(NBLK), dim3(NTHR), 0, stream,
                       h, u, Wih0, Wihr, Wfcb, bfc, c0, hhT, s,
                       x1B4, x2B4, chist4, xhist4, bar,
                       out + (size_t)sp * T_LEN * BATCH * OUTD);
  }
}

// Round 3
// 45875.598 us; speedup vs baseline: 6.5961x; 6.5961x over previous
//
#include <hip/hip_runtime.h>

#define T_LEN 512
#define BATCH 64
#define FEATD 512
#define HID   1024
#define G4H   4096
#define WINR  16
#define WLEN  33
#define OUTD  512
#define CATD  1536
#define NBLK  256
#define NTHR  512

typedef unsigned int uint32;
typedef unsigned short ushort16;
typedef short s16x8 __attribute__((ext_vector_type(8)));
typedef float f32x4 __attribute__((ext_vector_type(4)));

// ---------------- workspace layout (float offsets) ----------------
static const size_t OFF_U    = 0;
static const size_t OFF_HH   = 33554432;
static const size_t OFF_S    = OFF_HH + 786432;
static const size_t OFF_CB   = OFF_S  + 65536;
static const size_t OFF_X1   = OFF_CB + 16384;
static const size_t OFF_X2   = OFF_X1 + 32768;
static const size_t OFF_CK   = OFF_X2 + 32768;
static const size_t OFF_XK   = OFF_CK + 262144;
static const size_t OFF_BAR  = OFF_XK + 524288;
static const size_t OFF_WFCB = OFF_BAR + 1024;

__device__ __forceinline__ float sigmoidf_(float x) { return 1.0f / (1.0f + expf(-x)); }
__device__ __forceinline__ ushort16 f2bf(float f) {
  uint32 u = __float_as_uint(f);
  uint32 r = u + 0x7FFFu + ((u >> 16) & 1u);   // RNE
  return (ushort16)(r >> 16);
}
__device__ __forceinline__ float bf2f(ushort16 u) {
  return __uint_as_float(((uint32)u) << 16);
}

// ---- agent-scope (sc1, L2-bypassing) loads for cross-XCD-produced data ----
// Writers use plain stores; the barrier-arrival RMW carries RELEASE (vmcnt
// drain + wbl2). Readers bypass their possibly-stale local L2 via these.
__device__ __forceinline__ uint2 aload8(const void* p) {
  unsigned long long v = __hip_atomic_load((unsigned long long*)p,
                          __ATOMIC_RELAXED, __HIP_MEMORY_SCOPE_AGENT);
  uint2 r; r.x = (unsigned)(v & 0xffffffffull); r.y = (unsigned)(v >> 32);
  return r;
}
__device__ __forceinline__ float aload4f(const void* p) {
  return __hip_atomic_load((float*)p, __ATOMIC_RELAXED, __HIP_MEMORY_SCOPE_AGENT);
}

// ---------------- two-level grid barrier (256 blocks), NO L2 flush ----------------
// Arrival RMW is RELEASE: drains vmcnt and writes back the (nearly clean) L2
// so this block's plain stores reach L3 before the count is visible.
// No acquire/invalidate: consumers read cross-block data with sc1 loads, so
// the local L2 stays warm for constants (u, hin, Wfcb, weights, hhT, c0).
__device__ __forceinline__ void grid_barrier(unsigned* bar) {
  __syncthreads();
  if (threadIdx.x == 0) {
    unsigned* cnt  = bar + ((blockIdx.x & 7u) << 6);
    unsigned* gcnt = bar + 512;
    unsigned* gen  = bar + 576;
    unsigned g = __hip_atomic_load(gen, __ATOMIC_RELAXED, __HIP_MEMORY_SCOPE_AGENT);
    // RELEASE orders the gen read (vmcnt) and all prior stores before arrival.
    unsigned a = __hip_atomic_fetch_add(cnt, 1u, __ATOMIC_RELEASE, __HIP_MEMORY_SCOPE_AGENT);
    if (a == 31u) {
      __hip_atomic_store(cnt, 0u, __ATOMIC_RELAXED, __HIP_MEMORY_SCOPE_AGENT);
      unsigned ga = __hip_atomic_fetch_add(gcnt, 1u, __ATOMIC_ACQ_REL, __HIP_MEMORY_SCOPE_AGENT);
      if (ga == 7u) {
        __hip_atomic_store(gcnt, 0u, __ATOMIC_RELAXED, __HIP_MEMORY_SCOPE_AGENT);
        __hip_atomic_fetch_add(gen, 1u, __ATOMIC_RELEASE, __HIP_MEMORY_SCOPE_AGENT);
      } else {
        while (__hip_atomic_load(gen, __ATOMIC_RELAXED, __HIP_MEMORY_SCOPE_AGENT) == g)
          __builtin_amdgcn_s_sleep(2);
      }
    } else {
      while (__hip_atomic_load(gen, __ATOMIC_RELAXED, __HIP_MEMORY_SCOPE_AGENT) == g)
        __builtin_amdgcn_s_sleep(2);
    }
  }
  __syncthreads();
}

// ---------------- MFMA LSTM stage ----------------
// Block owns 16 W-rows: m = gate*4 + jl, row n = gate*HID + blockIdx*4 + jl.
// A-frags (bf16) pre-swizzled in LDS; B-frags via sc1 loads from global
// actB4 [K/4][64][4] bf16 (written by other blocks last stage).
// hhg[4]/c0v are per-thread register-preloaded constants (valid for wv<4).
template<int KSTEPS>
__device__ __forceinline__ void lstm_stage_mfma(
    const ushort16* __restrict__ wl,     // LDS [KSTEPS][64][8]
    const ushort16* __restrict__ actB4,  // global [K/4][64][4]
    const float* __restrict__ hhg,       // [4] preloaded (wv<4)
    float c0v,                           // preloaded (wv<4)
    ushort16* __restrict__ xoutB4,       // next act [H/4][64][4] or null
    ushort16* __restrict__ xhist_slot,   // [H/4][64][4] or null
    float* __restrict__ sOut,            // [B][HID] or null
    float* __restrict__ red)             // LDS [2][4][16][16]
{
  const int tid  = threadIdx.x;
  const int wv   = tid >> 6;
  const int lane = tid & 63;
  const int nt   = wv & 3;
  const int kh   = wv >> 2;
  const int quad = lane >> 4;
  const int b    = nt * 16 + (lane & 15);
  const int half = KSTEPS / 2;

  f32x4 acc0 = {0.f, 0.f, 0.f, 0.f};
  f32x4 acc1 = {0.f, 0.f, 0.f, 0.f};
  #pragma unroll 4
  for (int i = 0; i < half; i += 2) {
    const int ks0 = kh * half + i;
    const int ks1 = ks0 + 1;
    s16x8 a0 = *(const s16x8*)(wl + ((size_t)ks0 * 64 + lane) * 8);
    s16x8 a1 = *(const s16x8*)(wl + ((size_t)ks1 * 64 + lane) * 8);
    const int g0 = ks0 * 8 + quad * 2;
    const int g1 = ks1 * 8 + quad * 2;
    uint2 lo0 = aload8(actB4 + ((size_t)g0 * 64 + b) * 4);
    uint2 hi0 = aload8(actB4 + ((size_t)(g0 + 1) * 64 + b) * 4);
    uint2 lo1 = aload8(actB4 + ((size_t)g1 * 64 + b) * 4);
    uint2 hi1 = aload8(actB4 + ((size_t)(g1 + 1) * 64 + b) * 4);
    union { uint4 u; s16x8 v; } b0, b1;
    b0.u = make_uint4(lo0.x, lo0.y, hi0.x, hi0.y);
    b1.u = make_uint4(lo1.x, lo1.y, hi1.x, hi1.y);
    acc0 = __builtin_amdgcn_mfma_f32_16x16x32_bf16(a0, b0.v, acc0, 0, 0, 0);
    acc1 = __builtin_amdgcn_mfma_f32_16x16x32_bf16(a1, b1.v, acc1, 0, 0, 0);
  }
  f32x4 acc = acc0 + acc1;
  // partials: C-layout col=lane&15, row=quad*4+reg
  {
    float* rp = red + (((size_t)(kh * 4 + nt) * 16 + quad * 4) * 16) + (lane & 15);
    rp[0]  = acc[0];
    rp[16] = acc[1];
    rp[32] = acc[2];
    rp[48] = acc[3];
  }
  __syncthreads();
  if (wv < 4) {
    const int jl = wv;
    const int bb = lane;
    const int ntb = bb >> 4, col = bb & 15;
    float g[4];
    #pragma unroll
    for (int gate = 0; gate < 4; ++gate) {
      const int m = gate * 4 + jl;
      g[gate] = red[((size_t)(0 + ntb) * 16 + m) * 16 + col]
              + red[((size_t)(4 + ntb) * 16 + m) * 16 + col]
              + hhg[gate];
    }
    float cn = sigmoidf_(g[1]) * c0v + sigmoidf_(g[0]) * tanhf(g[2]);
    float hv = sigmoidf_(g[3]) * tanhf(cn);
    ushort16 hb = f2bf(hv);
    const int j = (blockIdx.x << 2) + jl;
    if (xoutB4)     xoutB4[((size_t)blockIdx.x * 64 + bb) * 4 + jl] = hb;
    if (xhist_slot) xhist_slot[((size_t)blockIdx.x * 64 + bb) * 4 + jl] = hb;
    if (sOut)       sOut[(size_t)bb * HID + j] = hv;
  }
}

// ---------------- FC head on the MFMA pipe ----------------
__device__ __forceinline__ void fc_step_mfma(int tp, int sub,
    const ushort16* __restrict__ ch4,   // [16][F/4][64][4]
    const ushort16* __restrict__ xh4,   // [16][H/4][64][4]
    const ushort16* __restrict__ Wfcb,  // [32][48][64][8]
    const float* __restrict__ bfc,
    float* __restrict__ outp, float* __restrict__ red)
{
  const int tid  = threadIdx.x;
  const int wv   = tid >> 6;
  const int lane = tid & 63;
  const int slot = tp & 15;
  const int ot   = sub >> 1;                 // 0..31
  const int tsel = wv & 1;                   // b-tile within half
  const int kq   = wv >> 1;                  // 0..3 K-quarter
  const int quad = lane >> 4;
  const int b    = ((sub & 1) * 2 + tsel) * 16 + (lane & 15);
  const ushort16* xs = xh4 + (size_t)slot * 65536;   // [256][64][4]
  const ushort16* cs = ch4 + (size_t)slot * 32768;   // [128][64][4]
  const ushort16* wa = Wfcb + ((size_t)ot * 48 + (size_t)kq * 12) * 512;

  f32x4 acc0 = {0.f, 0.f, 0.f, 0.f};
  f32x4 acc1 = {0.f, 0.f, 0.f, 0.f};
  #pragma unroll
  for (int i = 0; i < 12; i += 2) {
    const int ks0 = kq * 12 + i;
    const int ks1 = ks0 + 1;
    s16x8 a0 = *(const s16x8*)(wa + (size_t)i * 512 + (size_t)lane * 8);
    s16x8 a1 = *(const s16x8*)(wa + (size_t)(i + 1) * 512 + (size_t)lane * 8);
    const ushort16* s0p = (ks0 < 32) ? xs : cs;
    const ushort16* s1p = (ks1 < 32) ? xs : cs;
    const int gg0 = ((ks0 < 32) ? ks0 * 8 : (ks0 - 32) * 8) + quad * 2;
    const int gg1 = ((ks1 < 32) ? ks1 * 8 : (ks1 - 32) * 8) + quad * 2;
    uint2 lo0 = aload8(s0p + ((size_t)gg0 * 64 + b) * 4);
    uint2 hi0 = aload8(s0p + ((size_t)(gg0 + 1) * 64 + b) * 4);
    uint2 lo1 = aload8(s1p + ((size_t)gg1 * 64 + b) * 4);
    uint2 hi1 = aload8(s1p + ((size_t)(gg1 + 1) * 64 + b) * 4);
    union { uint4 u; s16x8 v; } b0, b1;
    b0.u = make_uint4(lo0.x, lo0.y, hi0.x, hi0.y);
    b1.u = make_uint4(lo1.x, lo1.y, hi1.x, hi1.y);
    acc0 = __builtin_amdgcn_mfma_f32_16x16x32_bf16(a0, b0.v, acc0, 0, 0, 0);
    acc1 = __builtin_amdgcn_mfma_f32_16x16x32_bf16(a1, b1.v, acc1, 0, 0, 0);
  }
  f32x4 acc = acc0 + acc1;
  {
    float* rp = red + ((size_t)wv * 16 + quad * 4) * 16 + (lane & 15);
    rp[0]  = acc[0];
    rp[16] = acc[1];
    rp[32] = acc[2];
    rp[48] = acc[3];
  }
  __syncthreads();
  {
    const int tl   = tid >> 8;          // b-tile
    const int bcol = (tid >> 4) & 15;
    const int m    = tid & 15;
    float v = bfc[ot * 16 + m];
    #pragma unroll
    for (int k4 = 0; k4 < 4; ++k4)
      v += red[((size_t)(k4 * 2 + tl) * 16 + m) * 16 + bcol];
    const int bo = ((sub & 1) * 2 + tl) * 16 + bcol;
    outp[((size_t)tp * BATCH + bo) * OUTD + ot * 16 + m] = fmaxf(v, 0.f);
  }
}

// ---------------- persistent per-speaker decoder ----------------
__global__ void __launch_bounds__(NTHR)
decoder_kernel(const float* __restrict__ hin, const float* __restrict__ u,
               const float* __restrict__ Wih0, const float* __restrict__ Wihr,
               const ushort16* __restrict__ Wfcb, const float* __restrict__ bfc,
               const float* __restrict__ c0, const float* __restrict__ hhT,
               float* __restrict__ s,
               ushort16* __restrict__ x1B4, ushort16* __restrict__ x2B4,
               ushort16* __restrict__ chist4, ushort16* __restrict__ xhist4,
               unsigned* __restrict__ bar, float* __restrict__ outp)
{
  __shared__ ushort16 wlds[40960];   // 80 KB: B[0,8192) C[8192,24576) D[24576,40960)
  __shared__ float s_l[HID];
  __shared__ float e_l[64];
  __shared__ float a_l[64];
  __shared__ float red[2 * 4 * 16 * 16];

  const int tid  = threadIdx.x;
  const int bid  = blockIdx.x;
  const int wv   = tid >> 6;
  const int lane = tid & 63;

  // ---- one-time: swizzle this block's weight slice into LDS (bf16 A-frags) ----
  for (int r = tid; r < 40960; r += NTHR) {
    int local, ksz; const float* Wsrc;
    if (r < 8192)        { local = r;         ksz = FEATD; Wsrc = Wih0; }
    else if (r < 24576)  { local = r - 8192;  ksz = HID;   Wsrc = Wihr; }
    else                 { local = r - 24576; ksz = HID;   Wsrc = Wihr + (size_t)G4H * HID; }
    const int ks   = local >> 9;
    const int li   = local & 511;
    const int ln   = li >> 3;
    const int jj   = li & 7;
    const int m    = ln & 15;
    const int quad = ln >> 4;
    const int k    = ks * 32 + quad * 8 + jj;
    const int n    = (m >> 2) * HID + (bid << 2) + (m & 3);
    wlds[r] = f2bf(Wsrc[(size_t)n * ksz + k]);
  }

  // ---- one-time: preload gate constants into registers (threads wv<4) ----
  float hh_r[3][4];
  float c0_r[3];
  if (wv < 4) {
    const int j  = (bid << 2) + wv;
    const int bb = lane;
    #pragma unroll
    for (int l = 0; l < 3; ++l) {
      #pragma unroll
      for (int gate = 0; gate < 4; ++gate)
        hh_r[l][gate] = hhT[((size_t)l * G4H + (size_t)gate * HID + j) * 64 + bb];
      c0_r[l] = c0[((size_t)l * BATCH + bb) * HID + j];
    }
  } else {
    #pragma unroll
    for (int l = 0; l < 3; ++l) {
      hh_r[l][0] = hh_r[l][1] = hh_r[l][2] = hh_r[l][3] = 0.f;
      c0_r[l] = 0.f;
    }
  }
  __syncthreads();

  for (int t = 0; t < T_LEN; ++t) {
    const int slot = t & 15;
    // ---- Stage A: attention (blocks 0..63) / FC bursts (blocks 64..255, every 3rd) ----
    if (bid < BATCH) {
      const int b = bid;
      // s was produced by other blocks last step -> sc1 loads
      s_l[tid]        = aload4f(s + (size_t)b * HID + tid);
      s_l[tid + NTHR] = aload4f(s + (size_t)b * HID + tid + NTHR);
      __syncthreads();
      for (int w = wv; w < WLEN; w += 8) {
        const int tau = t + w - WINR;
        float e = 0.f;   // zero-padded window -> e=0 participates in softmax
        if (tau >= 0 && tau < T_LEN) {
          const float* up = u + ((size_t)tau * BATCH + b) * HID;
          #pragma unroll
          for (int i = 0; i < 16; ++i) {
            const int hidx = lane + (i << 6);
            e += s_l[hidx] * up[hidx];
          }
          #pragma unroll
          for (int m = 32; m; m >>= 1) e += __shfl_xor(e, m);
        }
        if (lane == 0) e_l[w] = e;
      }
      __syncthreads();
      if (tid < 64) {
        float e = (tid < WLEN) ? e_l[tid] : -1e30f;
        float mx = e;
        #pragma unroll
        for (int m = 32; m; m >>= 1) mx = fmaxf(mx, __shfl_xor(mx, m));
        float p = (tid < WLEN) ? expf(e - mx) : 0.f;
        float sm = p;
        #pragma unroll
        for (int m = 32; m; m >>= 1) sm += __shfl_xor(sm, m);
        if (tid < WLEN) a_l[tid] = p / sm;
      }
      __syncthreads();
      {
        // context: branch-free bounds + dual FMA chains
        const int w0 = (t < WINR) ? (WINR - t) : 0;
        const int w1 = (T_LEN + WINR - t < WLEN) ? (T_LEN + WINR - t) : WLEN;
        const size_t hstep = (size_t)BATCH * FEATD;
        const float* hp = hin + ((size_t)(t + w0 - WINR) * BATCH + b) * FEATD + tid;
        float ca = 0.f, cb = 0.f;
        int w = w0;
        for (; w + 1 < w1; w += 2) {
          ca = fmaf(a_l[w],     hp[0],     ca);
          cb = fmaf(a_l[w + 1], hp[hstep], cb);
          hp += 2 * hstep;
        }
        if (w < w1) ca = fmaf(a_l[w], hp[0], ca);
        chist4[(size_t)slot * 32768 + ((size_t)(tid >> 2) * 64 + b) * 4 + (tid & 3)] = f2bf(ca + cb);
      }
    } else if (t >= 3 && t % 3 == 0) {
      const int fb = bid - BATCH;           // 0..191
      const int tp = t - 3 + (fb >> 6);     // 3 timesteps x 64 blocks
      fc_step_mfma(tp, fb & 63, chist4, xhist4, Wfcb, bfc, outp, red);
    }
    grid_barrier(bar);
    // ---- Stages B/C/D ----
    lstm_stage_mfma<16>(wlds, chist4 + (size_t)slot * 32768, hh_r[0], c0_r[0],
                        x1B4, nullptr, nullptr, red);
    grid_barrier(bar);
    lstm_stage_mfma<32>(wlds + 8192, x1B4, hh_r[1], c0_r[1],
                        x2B4, nullptr, nullptr, red);
    grid_barrier(bar);
    lstm_stage_mfma<32>(wlds + 24576, x2B4, hh_r[2], c0_r[2],
                        nullptr, xhist4 + (size_t)slot * 65536, s, red);
    grid_barrier(bar);
  }
  // ---- epilogue: FC for tp = 510, 511 on blocks 0..127 ----
  if (bid < 128) {
    const int tp = 510 + (bid >> 6);
    fc_step_mfma(tp, bid & 63, chist4, xhist4, Wfcb, bfc, outp, red);
  }
}

// ---------------- one-time: swizzle Wfc into bf16 MFMA A-frags ----------------
__global__ void __launch_bounds__(256)
wfcswz_kernel(const float* __restrict__ Wfc, ushort16* __restrict__ Wfcb)
{
  const int idx = blockIdx.x * 256 + threadIdx.x;   // 786432 total
  const int ot  = idx / 24576;
  const int r   = idx - ot * 24576;
  const int ks  = r >> 9;
  const int li  = r & 511;
  const int ln  = li >> 3;
  const int j   = li & 7;
  const int k   = ks * 32 + (ln >> 4) * 8 + j;
  const int o   = ot * 16 + (ln & 15);
  Wfcb[idx] = f2bf(Wfc[(size_t)o * CATD + k]);
}

// ---------------- u = h @ Wa_sp^T : [32768,512] x [1024,512]^T (fp32) ----------------
__global__ void __launch_bounds__(256)
gemm_u_kernel(const float* __restrict__ A, const float* __restrict__ Bm,
              float* __restrict__ C)
{
  __shared__ float Al[64 * 68];
  __shared__ float Bl[64 * 68];
  const int tid = threadIdx.x;
  const int m0 = blockIdx.x * 64;
  const int n0 = blockIdx.y * 64;
  const int tx = tid & 15, ty = tid >> 4;
  float acc[4][4] = {};
  for (int kc = 0; kc < 512; kc += 64) {
    #pragma unroll
    for (int p = 0; p < 4; ++p) {
      const int row = p * 16 + (tid >> 4);
      const int kq  = (tid & 15) * 4;
      float4 v = *(const float4*)(A + (size_t)(m0 + row) * 512 + kc + kq);
      Al[(kq + 0) * 68 + row] = v.x;
      Al[(kq + 1) * 68 + row] = v.y;
      Al[(kq + 2) * 68 + row] = v.z;
      Al[(kq + 3) * 68 + row] = v.w;
      float4 w = *(const float4*)(Bm + (size_t)(n0 + row) * 512 + kc + kq);
      Bl[(kq + 0) * 68 + row] = w.x;
      Bl[(kq + 1) * 68 + row] = w.y;
      Bl[(kq + 2) * 68 + row] = w.z;
      Bl[(kq + 3) * 68 + row] = w.w;
    }
    __syncthreads();
    #pragma unroll 8
    for (int k = 0; k < 64; ++k) {
      float4 av = *(const float4*)(&Al[k * 68 + ty * 4]);
      float4 bv = *(const float4*)(&Bl[k * 68 + tx * 4]);
      float aa[4] = {av.x, av.y, av.z, av.w};
      float bb[4] = {bv.x, bv.y, bv.z, bv.w};
      #pragma unroll
      for (int i = 0; i < 4; ++i)
        #pragma unroll
        for (int jj = 0; jj < 4; ++jj)
          acc[i][jj] = fmaf(aa[i], bb[jj], acc[i][jj]);
    }
    __syncthreads();
  }
  #pragma unroll
  for (int i = 0; i < 4; ++i) {
    float4 r = {acc[i][0], acc[i][1], acc[i][2], acc[i][3]};
    *(float4*)(C + (size_t)(m0 + ty * 4 + i) * 1024 + n0 + tx * 4) = r;
  }
}

// ------- hhT[l][n][b] = h0[l,b,:] . Whh_l[n,:] + bih_l[n] + bhh_l[n] -------
__global__ void __launch_bounds__(256)
hhconst_kernel(const float* __restrict__ Whh0, const float* __restrict__ Whr,
               const float* __restrict__ bih0, const float* __restrict__ bhh0,
               const float* __restrict__ bihr, const float* __restrict__ bhhr,
               const float* __restrict__ h0, float* __restrict__ hh)
{
  const int idx = blockIdx.x * 256 + threadIdx.x;   // 786432 total
  const int b = idx & 63;
  const int n = (idx >> 6) & 4095;
  const int l = idx >> 18;
  const float* W = (l == 0) ? (Whh0 + (size_t)n * HID)
                            : (Whr + ((size_t)(l - 1) * G4H + n) * HID);
  float acc = ((l == 0) ? bih0[n] : bihr[(l - 1) * G4H + n])
            + ((l == 0) ? bhh0[n] : bhhr[(l - 1) * G4H + n]);
  const float* hr = h0 + ((size_t)l * BATCH + b) * HID;
  #pragma unroll 2
  for (int k = 0; k < HID; k += 4) {
    float4 a4 = *(const float4*)(hr + k);
    float4 w4 = *(const float4*)(W + k);
    acc += a4.x * w4.x + a4.y * w4.y + a4.z * w4.z + a4.w * w4.w;
  }
  hh[idx] = acc;    // (l*G4H + n)*64 + b  -> k-major, coalesced
}

__global__ void __launch_bounds__(256)
init_kernel(const float* __restrict__ s0, float* __restrict__ s, unsigned* __restrict__ bar)
{
  const int gid = blockIdx.x * 256 + threadIdx.x;
  if (gid < BATCH * HID) s[gid] = s0[gid];
  if (blockIdx.x == 0)
    for (int i = threadIdx.x; i < 1024; i += 256) bar[i] = 0u;
}

extern "C" void kernel_launch(void* const* d_in, const int* in_sizes, int n_in,
                              void* d_out, int out_size, void* d_ws, size_t ws_size,
                              hipStream_t stream) {
  (void)in_sizes; (void)n_in; (void)out_size; (void)ws_size;
  const float* h    = (const float*)d_in[0];
  const float* Wa   = (const float*)d_in[1];
  const float* Wih0 = (const float*)d_in[2];
  const float* Whh0 = (const float*)d_in[3];
  const float* bih0 = (const float*)d_in[4];
  const float* bhh0 = (const float*)d_in[5];
  const float* Wihr = (const float*)d_in[6];
  const float* Whhr = (const float*)d_in[7];
  const float* bihr = (const float*)d_in[8];
  const float* bhhr = (const float*)d_in[9];
  const float* Wfc  = (const float*)d_in[10];
  const float* bfc  = (const float*)d_in[11];
  const float* s0   = (const float*)d_in[12];
  const float* h0   = (const float*)d_in[13];
  const float* c0   = (const float*)d_in[14];
  float* out = (float*)d_out;
  float* ws  = (float*)d_ws;

  float* u         = ws + OFF_U;
  float* hhT       = ws + OFF_HH;
  float* s         = ws + OFF_S;
  ushort16* x1B4   = (ushort16*)(ws + OFF_X1);
  ushort16* x2B4   = (ushort16*)(ws + OFF_X2);
  ushort16* chist4 = (ushort16*)(ws + OFF_CK);
  ushort16* xhist4 = (ushort16*)(ws + OFF_XK);
  unsigned* bar    = (unsigned*)(ws + OFF_BAR);
  ushort16* Wfcb   = (ushort16*)(ws + OFF_WFCB);

  hipLaunchKernelGGL(init_kernel, dim3(256), dim3(256), 0, stream, s0, s, bar);
  hipLaunchKernelGGL(hhconst_kernel, dim3(3072), dim3(256), 0, stream,
                     Whh0, Whhr, bih0, bhh0, bihr, bhhr, h0, hhT);
  hipLaunchKernelGGL(wfcswz_kernel, dim3(3072), dim3(256), 0, stream, Wfc, Wfcb);
  for (int sp = 0; sp < 2; ++sp) {
    hipLaunchKernelGGL(gemm_u_kernel, dim3(512, 16), dim3(256), 0, stream,
                       h, Wa + (size_t)sp * HID * FEATD, u);
    hipLaunchKernelGGL(decoder_kernel, dim3(NBLK), dim3(NTHR), 0, stream,
                       h, u, Wih0, Wihr, Wfcb, bfc, c0, hhT, s,
                       x1B4, x2B4, chist4, xhist4, bar,
                       out + (size_t)sp * T_LEN * BATCH * OUTD);
  }
}

// Round 8
// 36431.592 us; speedup vs baseline: 8.3060x; 1.2592x over previous
//
#include <hip/hip_runtime.h>

#define T_LEN 512
#define BATCH 64
#define FEATD 512
#define HID   1024
#define G4H   4096
#define WINR  16
#define WLEN  33
#define OUTD  512
#define CATD  1536
#define NBLK  256
#define NTHR  512

typedef unsigned int uint32;
typedef unsigned long long u64;
typedef unsigned short ushort16;
typedef short s16x8 __attribute__((ext_vector_type(8)));
typedef float f32x4 __attribute__((ext_vector_type(4)));

// ---------------- workspace layout (float offsets) ----------------
static const size_t OFF_U    = 0;
static const size_t OFF_HH   = 33554432;
static const size_t OFF_S    = OFF_HH + 786432;
static const size_t OFF_CB   = OFF_S  + 65536;
static const size_t OFF_X1   = OFF_CB + 16384;
static const size_t OFF_X2   = OFF_X1 + 32768;
static const size_t OFF_CK   = OFF_X2 + 32768;
static const size_t OFF_XK   = OFF_CK + 262144;
static const size_t OFF_BAR  = OFF_XK + 524288;
static const size_t OFF_WFCB = OFF_BAR + 1024;

__device__ __forceinline__ float sigmoidf_(float x) { return 1.0f / (1.0f + expf(-x)); }
__device__ __forceinline__ ushort16 f2bf(float f) {
  uint32 u = __float_as_uint(f);
  uint32 r = u + 0x7FFFu + ((u >> 16) & 1u);   // RNE
  return (ushort16)(r >> 16);
}

// ---- agent-scope (sc1, L2-bypassing) ops for cross-block data ----
// ALL cross-block-visible stores are relaxed agent atomics (write to L3
// directly, never dirty in L2). __syncthreads() drains each wave's vmcnt
// before s_barrier, so by barrier-arrival every store is at the point of
// coherence -> the arrival RMW can be fully RELAXED: no buffer_wbl2, ever.
__device__ __forceinline__ uint2 aload8(const void* p) {
  u64 v = __hip_atomic_load((const u64*)p, __ATOMIC_RELAXED, __HIP_MEMORY_SCOPE_AGENT);
  uint2 r; r.x = (unsigned)(v & 0xffffffffull); r.y = (unsigned)(v >> 32);
  return r;
}
__device__ __forceinline__ float aload4f(const void* p) {
  return __hip_atomic_load((const float*)p, __ATOMIC_RELAXED, __HIP_MEMORY_SCOPE_AGENT);
}
__device__ __forceinline__ void astore8(void* p, u64 v) {
  __hip_atomic_store((u64*)p, v, __ATOMIC_RELAXED, __HIP_MEMORY_SCOPE_AGENT);
}
__device__ __forceinline__ void astore4f(void* p, float v) {
  __hip_atomic_store((float*)p, v, __ATOMIC_RELAXED, __HIP_MEMORY_SCOPE_AGENT);
}

// ---------------- two-level grid barrier (256 blocks), fully relaxed ----------------
__device__ __forceinline__ void grid_barrier(unsigned* bar) {
  __syncthreads();   // drains vmcnt per wave -> sc1 stores are at L3
  if (threadIdx.x == 0) {
    unsigned* cnt  = bar + ((blockIdx.x & 7u) << 6);
    unsigned* gcnt = bar + 512;
    unsigned* gen  = bar + 576;
    unsigned g = __hip_atomic_load(gen, __ATOMIC_RELAXED, __HIP_MEMORY_SCOPE_AGENT);
    unsigned a = __hip_atomic_fetch_add(cnt, 1u, __ATOMIC_RELAXED, __HIP_MEMORY_SCOPE_AGENT);
    if (a == 31u) {
      __hip_atomic_store(cnt, 0u, __ATOMIC_RELAXED, __HIP_MEMORY_SCOPE_AGENT);
      unsigned ga = __hip_atomic_fetch_add(gcnt, 1u, __ATOMIC_RELAXED, __HIP_MEMORY_SCOPE_AGENT);
      if (ga == 7u) {
        __hip_atomic_store(gcnt, 0u, __ATOMIC_RELAXED, __HIP_MEMORY_SCOPE_AGENT);
        __hip_atomic_fetch_add(gen, 1u, __ATOMIC_RELAXED, __HIP_MEMORY_SCOPE_AGENT);
      } else {
        while (__hip_atomic_load(gen, __ATOMIC_RELAXED, __HIP_MEMORY_SCOPE_AGENT) == g)
          __builtin_amdgcn_s_sleep(2);
      }
    } else {
      while (__hip_atomic_load(gen, __ATOMIC_RELAXED, __HIP_MEMORY_SCOPE_AGENT) == g)
        __builtin_amdgcn_s_sleep(2);
    }
  }
  __syncthreads();
}

// ---------------- MFMA LSTM stage ----------------
// Block owns 16 W-rows: m = gate*4 + jl, row n = gate*HID + blockIdx*4 + jl.
// A-frags (bf16) pre-swizzled in LDS; B-frags via sc1 loads from global
// actB4 [K/4][64][4] bf16 (written by other blocks last stage).
// Outputs: gate math in waves 0-3, hv staged via hv_l LDS, wave 0 packs
// 4 bf16 -> one 8B sc1 store per b.
template<int KSTEPS>
__device__ __forceinline__ void lstm_stage_mfma(
    const ushort16* __restrict__ wl,     // LDS [KSTEPS][64][8]
    const ushort16* __restrict__ actB4,  // global [K/4][64][4]
    const float* __restrict__ hhg,       // [4] preloaded (wv<4)
    float c0v,                           // preloaded (wv<4)
    ushort16* __restrict__ xoutB4,       // next act [H/4][64][4] or null
    ushort16* __restrict__ xhist_slot,   // [H/4][64][4] or null
    float* __restrict__ sOut,            // [B][HID] or null
    float* __restrict__ red,             // LDS [2][4][16][16]
    float* __restrict__ hv_l)            // LDS [4][64]
{
  const int tid  = threadIdx.x;
  const int wv   = tid >> 6;
  const int lane = tid & 63;
  const int nt   = wv & 3;
  const int kh   = wv >> 2;
  const int quad = lane >> 4;
  const int b    = nt * 16 + (lane & 15);
  const int half = KSTEPS / 2;

  f32x4 acc0 = {0.f, 0.f, 0.f, 0.f};
  f32x4 acc1 = {0.f, 0.f, 0.f, 0.f};
  #pragma unroll
  for (int i = 0; i < half; i += 2) {
    const int ks0 = kh * half + i;
    const int ks1 = ks0 + 1;
    s16x8 a0 = *(const s16x8*)(wl + ((size_t)ks0 * 64 + lane) * 8);
    s16x8 a1 = *(const s16x8*)(wl + ((size_t)ks1 * 64 + lane) * 8);
    const int g0 = ks0 * 8 + quad * 2;
    const int g1 = ks1 * 8 + quad * 2;
    uint2 lo0 = aload8(actB4 + ((size_t)g0 * 64 + b) * 4);
    uint2 hi0 = aload8(actB4 + ((size_t)(g0 + 1) * 64 + b) * 4);
    uint2 lo1 = aload8(actB4 + ((size_t)g1 * 64 + b) * 4);
    uint2 hi1 = aload8(actB4 + ((size_t)(g1 + 1) * 64 + b) * 4);
    union { uint4 u; s16x8 v; } b0, b1;
    b0.u = make_uint4(lo0.x, lo0.y, hi0.x, hi0.y);
    b1.u = make_uint4(lo1.x, lo1.y, hi1.x, hi1.y);
    acc0 = __builtin_amdgcn_mfma_f32_16x16x32_bf16(a0, b0.v, acc0, 0, 0, 0);
    acc1 = __builtin_amdgcn_mfma_f32_16x16x32_bf16(a1, b1.v, acc1, 0, 0, 0);
  }
  f32x4 acc = acc0 + acc1;
  // partials: C-layout col=lane&15, row=quad*4+reg
  {
    float* rp = red + (((size_t)(kh * 4 + nt) * 16 + quad * 4) * 16) + (lane & 15);
    rp[0]  = acc[0];
    rp[16] = acc[1];
    rp[32] = acc[2];
    rp[48] = acc[3];
  }
  __syncthreads();
  if (wv < 4) {
    const int jl = wv;
    const int bb = lane;
    const int ntb = bb >> 4, col = bb & 15;
    float g[4];
    #pragma unroll
    for (int gate = 0; gate < 4; ++gate) {
      const int m = gate * 4 + jl;
      g[gate] = red[((size_t)(0 + ntb) * 16 + m) * 16 + col]
              + red[((size_t)(4 + ntb) * 16 + m) * 16 + col]
              + hhg[gate];
    }
    float cn = sigmoidf_(g[1]) * c0v + sigmoidf_(g[0]) * tanhf(g[2]);
    float hv = sigmoidf_(g[3]) * tanhf(cn);
    if (sOut) astore4f(sOut + (size_t)bb * HID + (blockIdx.x << 2) + jl, hv);
    hv_l[jl * 64 + bb] = hv;
  }
  if (xoutB4 || xhist_slot) {
    __syncthreads();
    if (wv == 0) {
      const int bb = lane;
      uint32 lo = (uint32)f2bf(hv_l[0 * 64 + bb]) | ((uint32)f2bf(hv_l[1 * 64 + bb]) << 16);
      uint32 hi = (uint32)f2bf(hv_l[2 * 64 + bb]) | ((uint32)f2bf(hv_l[3 * 64 + bb]) << 16);
      u64 pk = ((u64)hi << 32) | (u64)lo;
      if (xoutB4)     astore8(xoutB4 + ((size_t)blockIdx.x * 64 + bb) * 4, pk);
      if (xhist_slot) astore8(xhist_slot + ((size_t)blockIdx.x * 64 + bb) * 4, pk);
    }
  }
}

// ---------------- FC head on the MFMA pipe ----------------
__device__ __forceinline__ void fc_step_mfma(int tp, int sub,
    const ushort16* __restrict__ ch4,   // [16][F/4][64][4]
    const ushort16* __restrict__ xh4,   // [16][H/4][64][4]
    const ushort16* __restrict__ Wfcb,  // [32][48][64][8]
    const float* __restrict__ bfc,
    float* __restrict__ outp, float* __restrict__ red)
{
  const int tid  = threadIdx.x;
  const int wv   = tid >> 6;
  const int lane = tid & 63;
  const int slot = tp & 15;
  const int ot   = sub >> 1;                 // 0..31
  const int tsel = wv & 1;                   // b-tile within half
  const int kq   = wv >> 1;                  // 0..3 K-quarter
  const int quad = lane >> 4;
  const int b    = ((sub & 1) * 2 + tsel) * 16 + (lane & 15);
  const ushort16* xs = xh4 + (size_t)slot * 65536;   // [256][64][4]
  const ushort16* cs = ch4 + (size_t)slot * 32768;   // [128][64][4]
  const ushort16* wa = Wfcb + ((size_t)ot * 48 + (size_t)kq * 12) * 512;

  f32x4 acc0 = {0.f, 0.f, 0.f, 0.f};
  f32x4 acc1 = {0.f, 0.f, 0.f, 0.f};
  #pragma unroll
  for (int i = 0; i < 12; i += 2) {
    const int ks0 = kq * 12 + i;
    const int ks1 = ks0 + 1;
    s16x8 a0 = *(const s16x8*)(wa + (size_t)i * 512 + (size_t)lane * 8);
    s16x8 a1 = *(const s16x8*)(wa + (size_t)(i + 1) * 512 + (size_t)lane * 8);
    const ushort16* s0p = (ks0 < 32) ? xs : cs;
    const ushort16* s1p = (ks1 < 32) ? xs : cs;
    const int gg0 = ((ks0 < 32) ? ks0 * 8 : (ks0 - 32) * 8) + quad * 2;
    const int gg1 = ((ks1 < 32) ? ks1 * 8 : (ks1 - 32) * 8) + quad * 2;
    uint2 lo0 = aload8(s0p + ((size_t)gg0 * 64 + b) * 4);
    uint2 hi0 = aload8(s0p + ((size_t)(gg0 + 1) * 64 + b) * 4);
    uint2 lo1 = aload8(s1p + ((size_t)gg1 * 64 + b) * 4);
    uint2 hi1 = aload8(s1p + ((size_t)(gg1 + 1) * 64 + b) * 4);
    union { uint4 u; s16x8 v; } b0, b1;
    b0.u = make_uint4(lo0.x, lo0.y, hi0.x, hi0.y);
    b1.u = make_uint4(lo1.x, lo1.y, hi1.x, hi1.y);
    acc0 = __builtin_amdgcn_mfma_f32_16x16x32_bf16(a0, b0.v, acc0, 0, 0, 0);
    acc1 = __builtin_amdgcn_mfma_f32_16x16x32_bf16(a1, b1.v, acc1, 0, 0, 0);
  }
  f32x4 acc = acc0 + acc1;
  {
    float* rp = red + ((size_t)wv * 16 + quad * 4) * 16 + (lane & 15);
    rp[0]  = acc[0];
    rp[16] = acc[1];
    rp[32] = acc[2];
    rp[48] = acc[3];
  }
  __syncthreads();
  {
    const int tl   = tid >> 8;          // b-tile
    const int bcol = (tid >> 4) & 15;
    const int m    = tid & 15;
    float v = bfc[ot * 16 + m];
    #pragma unroll
    for (int k4 = 0; k4 < 4; ++k4)
      v += red[((size_t)(k4 * 2 + tl) * 16 + m) * 16 + bcol];
    const int bo = ((sub & 1) * 2 + tl) * 16 + bcol;
    outp[((size_t)tp * BATCH + bo) * OUTD + ot * 16 + m] = fmaxf(v, 0.f);
  }
}

// ---------------- persistent per-speaker decoder ----------------
__global__ void __launch_bounds__(NTHR)
decoder_kernel(const float* __restrict__ hin, const float* __restrict__ u,
               const float* __restrict__ Wih0, const float* __restrict__ Wihr,
               const ushort16* __restrict__ Wfcb, const float* __restrict__ bfc,
               const float* __restrict__ c0, const float* __restrict__ hhT,
               float* __restrict__ s,
               ushort16* __restrict__ x1B4, ushort16* __restrict__ x2B4,
               ushort16* __restrict__ chist4, ushort16* __restrict__ xhist4,
               unsigned* __restrict__ bar, float* __restrict__ outp)
{
  __shared__ ushort16 wlds[40960];   // 80 KB: B[0,8192) C[8192,24576) D[24576,40960)
  __shared__ float s_l[HID];
  __shared__ float e_l[64];
  __shared__ float a_l[64];
  __shared__ float red[2 * 4 * 16 * 16];
  __shared__ float c_l[FEATD];
  __shared__ float hv_l[4 * 64];

  const int tid  = threadIdx.x;
  const int bid  = blockIdx.x;
  const int wv   = tid >> 6;
  const int lane = tid & 63;

  // ---- one-time: swizzle this block's weight slice into LDS (bf16 A-frags) ----
  for (int r = tid; r < 40960; r += NTHR) {
    int local, ksz; const float* Wsrc;
    if (r < 8192)        { local = r;         ksz = FEATD; Wsrc = Wih0; }
    else if (r < 24576)  { local = r - 8192;  ksz = HID;   Wsrc = Wihr; }
    else                 { local = r - 24576; ksz = HID;   Wsrc = Wihr + (size_t)G4H * HID; }
    const int ks   = local >> 9;
    const int li   = local & 511;
    const int ln   = li >> 3;
    const int jj   = li & 7;
    const int m    = ln & 15;
    const int quad = ln >> 4;
    const int k    = ks * 32 + quad * 8 + jj;
    const int n    = (m >> 2) * HID + (bid << 2) + (m & 3);
    wlds[r] = f2bf(Wsrc[(size_t)n * ksz + k]);
  }

  // ---- one-time: preload gate constants into registers (threads wv<4) ----
  float hh_r[3][4];
  float c0_r[3];
  if (wv < 4) {
    const int j  = (bid << 2) + wv;
    const int bb = lane;
    #pragma unroll
    for (int l = 0; l < 3; ++l) {
      #pragma unroll
      for (int gate = 0; gate < 4; ++gate)
        hh_r[l][gate] = hhT[((size_t)l * G4H + (size_t)gate * HID + j) * 64 + bb];
      c0_r[l] = c0[((size_t)l * BATCH + bb) * HID + j];
    }
  } else {
    #pragma unroll
    for (int l = 0; l < 3; ++l) {
      hh_r[l][0] = hh_r[l][1] = hh_r[l][2] = hh_r[l][3] = 0.f;
      c0_r[l] = 0.f;
    }
  }
  __syncthreads();

  for (int t = 0; t < T_LEN; ++t) {
    const int slot = t & 15;
    // ---- Stage A: attention (blocks 0..63) / FC bursts (blocks 64..255, every 3rd) ----
    if (bid < BATCH) {
      const int b = bid;
      // s was produced by other blocks last step -> sc1 loads
      s_l[tid]        = aload4f(s + (size_t)b * HID + tid);
      s_l[tid + NTHR] = aload4f(s + (size_t)b * HID + tid + NTHR);
      __syncthreads();
      for (int w = wv; w < WLEN; w += 8) {
        const int tau = t + w - WINR;
        float e = 0.f;   // zero-padded window -> e=0 participates in softmax
        if (tau >= 0 && tau < T_LEN) {
          const float* up = u + ((size_t)tau * BATCH + b) * HID;
          #pragma unroll
          for (int i = 0; i < 16; ++i) {
            const int hidx = lane + (i << 6);
            e += s_l[hidx] * up[hidx];
          }
          #pragma unroll
          for (int m = 32; m; m >>= 1) e += __shfl_xor(e, m);
        }
        if (lane == 0) e_l[w] = e;
      }
      __syncthreads();
      if (tid < 64) {
        float e = (tid < WLEN) ? e_l[tid] : -1e30f;
        float mx = e;
        #pragma unroll
        for (int m = 32; m; m >>= 1) mx = fmaxf(mx, __shfl_xor(mx, m));
        float p = (tid < WLEN) ? expf(e - mx) : 0.f;
        float sm = p;
        #pragma unroll
        for (int m = 32; m; m >>= 1) sm += __shfl_xor(sm, m);
        if (tid < WLEN) a_l[tid] = p / sm;
      }
      __syncthreads();
      {
        // context: branch-free bounds + dual FMA chains
        const int w0 = (t < WINR) ? (WINR - t) : 0;
        const int w1 = (T_LEN + WINR - t < WLEN) ? (T_LEN + WINR - t) : WLEN;
        const size_t hstep = (size_t)BATCH * FEATD;
        const float* hp = hin + ((size_t)(t + w0 - WINR) * BATCH + b) * FEATD + tid;
        float ca = 0.f, cb = 0.f;
        int w = w0;
        for (; w + 1 < w1; w += 2) {
          ca = fmaf(a_l[w],     hp[0],     ca);
          cb = fmaf(a_l[w + 1], hp[hstep], cb);
          hp += 2 * hstep;
        }
        if (w < w1) ca = fmaf(a_l[w], hp[0], ca);
        c_l[tid] = ca + cb;
      }
      __syncthreads();
      if (tid < 128) {
        // pack 4 consecutive f (one B4 group) -> one 8B sc1 store
        uint32 lo = (uint32)f2bf(c_l[4 * tid + 0]) | ((uint32)f2bf(c_l[4 * tid + 1]) << 16);
        uint32 hi = (uint32)f2bf(c_l[4 * tid + 2]) | ((uint32)f2bf(c_l[4 * tid + 3]) << 16);
        u64 pk = ((u64)hi << 32) | (u64)lo;
        astore8(chist4 + (size_t)slot * 32768 + ((size_t)tid * 64 + b) * 4, pk);
      }
    } else if (t >= 3 && t % 3 == 0) {
      const int fb = bid - BATCH;           // 0..191
      const int tp = t - 3 + (fb >> 6);     // 3 timesteps x 64 blocks
      fc_step_mfma(tp, fb & 63, chist4, xhist4, Wfcb, bfc, outp, red);
    }
    grid_barrier(bar);
    // ---- Stages B/C/D ----
    lstm_stage_mfma<16>(wlds, chist4 + (size_t)slot * 32768, hh_r[0], c0_r[0],
                        x1B4, nullptr, nullptr, red, hv_l);
    grid_barrier(bar);
    lstm_stage_mfma<32>(wlds + 8192, x1B4, hh_r[1], c0_r[1],
                        x2B4, nullptr, nullptr, red, hv_l);
    grid_barrier(bar);
    lstm_stage_mfma<32>(wlds + 24576, x2B4, hh_r[2], c0_r[2],
                        nullptr, xhist4 + (size_t)slot * 65536, s, red, hv_l);
    grid_barrier(bar);
  }
  // ---- epilogue: FC for tp = 510, 511 on blocks 0..127 ----
  if (bid < 128) {
    const int tp = 510 + (bid >> 6);
    fc_step_mfma(tp, bid & 63, chist4, xhist4, Wfcb, bfc, outp, red);
  }
}

// ---------------- one-time: swizzle Wfc into bf16 MFMA A-frags ----------------
__global__ void __launch_bounds__(256)
wfcswz_kernel(const float* __restrict__ Wfc, ushort16* __restrict__ Wfcb)
{
  const int idx = blockIdx.x * 256 + threadIdx.x;   // 786432 total
  const int ot  = idx / 24576;
  const int r   = idx - ot * 24576;
  const int ks  = r >> 9;
  const int li  = r & 511;
  const int ln  = li >> 3;
  const int j   = li & 7;
  const int k   = ks * 32 + (ln >> 4) * 8 + j;
  const int o   = ot * 16 + (ln & 15);
  Wfcb[idx] = f2bf(Wfc[(size_t)o * CATD + k]);
}

// ---------------- u = h @ Wa_sp^T : [32768,512] x [1024,512]^T (fp32) ----------------
__global__ void __launch_bounds__(256)
gemm_u_kernel(const float* __restrict__ A, const float* __restrict__ Bm,
              float* __restrict__ C)
{
  __shared__ float Al[64 * 68];
  __shared__ float Bl[64 * 68];
  const int tid = threadIdx.x;
  const int m0 = blockIdx.x * 64;
  const int n0 = blockIdx.y * 64;
  const int tx = tid & 15, ty = tid >> 4;
  float acc[4][4] = {};
  for (int kc = 0; kc < 512; kc += 64) {
    #pragma unroll
    for (int p = 0; p < 4; ++p) {
      const int row = p * 16 + (tid >> 4);
      const int kq  = (tid & 15) * 4;
      float4 v = *(const float4*)(A + (size_t)(m0 + row) * 512 + kc + kq);
      Al[(kq + 0) * 68 + row] = v.x;
      Al[(kq + 1) * 68 + row] = v.y;
      Al[(kq + 2) * 68 + row] = v.z;
      Al[(kq + 3) * 68 + row] = v.w;
      float4 w = *(const float4*)(Bm + (size_t)(n0 + row) * 512 + kc + kq);
      Bl[(kq + 0) * 68 + row] = w.x;
      Bl[(kq + 1) * 68 + row] = w.y;
      Bl[(kq + 2) * 68 + row] = w.z;
      Bl[(kq + 3) * 68 + row] = w.w;
    }
    __syncthreads();
    #pragma unroll 8
    for (int k = 0; k < 64; ++k) {
      float4 av = *(const float4*)(&Al[k * 68 + ty * 4]);
      float4 bv = *(const float4*)(&Bl[k * 68 + tx * 4]);
      float aa[4] = {av.x, av.y, av.z, av.w};
      float bb[4] = {bv.x, bv.y, bv.z, bv.w};
      #pragma unroll
      for (int i = 0; i < 4; ++i)
        #pragma unroll
        for (int jj = 0; jj < 4; ++jj)
          acc[i][jj] = fmaf(aa[i], bb[jj], acc[i][jj]);
    }
    __syncthreads();
  }
  #pragma unroll
  for (int i = 0; i < 4; ++i) {
    float4 r = {acc[i][0], acc[i][1], acc[i][2], acc[i][3]};
    *(float4*)(C + (size_t)(m0 + ty * 4 + i) * 1024 + n0 + tx * 4) = r;
  }
}

// ------- hhT[l][n][b] = h0[l,b,:] . Whh_l[n,:] + bih_l[n] + bhh_l[n] -------
__global__ void __launch_bounds__(256)
hhconst_kernel(const float* __restrict__ Whh0, const float* __restrict__ Whr,
               const float* __restrict__ bih0, const float* __restrict__ bhh0,
               const float* __restrict__ bihr, const float* __restrict__ bhhr,
               const float* __restrict__ h0, float* __restrict__ hh)
{
  const int idx = blockIdx.x * 256 + threadIdx.x;   // 786432 total
  const int b = idx & 63;
  const int n = (idx >> 6) & 4095;
  const int l = idx >> 18;
  const float* W = (l == 0) ? (Whh0 + (size_t)n * HID)
                            : (Whr + ((size_t)(l - 1) * G4H + n) * HID);
  float acc = ((l == 0) ? bih0[n] : bihr[(l - 1) * G4H + n])
            + ((l == 0) ? bhh0[n] : bhhr[(l - 1) * G4H + n]);
  const float* hr = h0 + ((size_t)l * BATCH + b) * HID;
  #pragma unroll 2
  for (int k = 0; k < HID; k += 4) {
    float4 a4 = *(const float4*)(hr + k);
    float4 w4 = *(const float4*)(W + k);
    acc += a4.x * w4.x + a4.y * w4.y + a4.z * w4.z + a4.w * w4.w;
  }
  hh[idx] = acc;    // (l*G4H + n)*64 + b  -> k-major, coalesced
}

__global__ void __launch_bounds__(256)
init_kernel(const float* __restrict__ s0, float* __restrict__ s, unsigned* __restrict__ bar)
{
  const int gid = blockIdx.x * 256 + threadIdx.x;
  if (gid < BATCH * HID) s[gid] = s0[gid];
  if (blockIdx.x == 0)
    for (int i = threadIdx.x; i < 1024; i += 256) bar[i] = 0u;
}

extern "C" void kernel_launch(void* const* d_in, const int* in_sizes, int n_in,
                              void* d_out, int out_size, void* d_ws, size_t ws_size,
                              hipStream_t stream) {
  (void)in_sizes; (void)n_in; (void)out_size; (void)ws_size;
  const float* h    = (const float*)d_in[0];
  const float* Wa   = (const float*)d_in[1];
  const float* Wih0 = (const float*)d_in[2];
  const float* Whh0 = (const float*)d_in[3];
  const float* bih0 = (const float*)d_in[4];
  const float* bhh0 = (const float*)d_in[5];
  const float* Wihr = (const float*)d_in[6];
  const float* Whhr = (const float*)d_in[7];
  const float* bihr = (const float*)d_in[8];
  const float* bhhr = (const float*)d_in[9];
  const float* Wfc  = (const float*)d_in[10];
  const float* bfc  = (const float*)d_in[11];
  const float* s0   = (const float*)d_in[12];
  const float* h0   = (const float*)d_in[13];
  const float* c0   = (const float*)d_in[14];
  float* out = (float*)d_out;
  float* ws  = (float*)d_ws;

  float* u         = ws + OFF_U;
  float* hhT       = ws + OFF_HH;
  float* s         = ws + OFF_S;
  ushort16* x1B4   = (ushort16*)(ws + OFF_X1);
  ushort16* x2B4   = (ushort16*)(ws + OFF_X2);
  ushort16* chist4 = (ushort16*)(ws + OFF_CK);
  ushort16* xhist4 = (ushort16*)(ws + OFF_XK);
  unsigned* bar    = (unsigned*)(ws + OFF_BAR);
  ushort16* Wfcb   = (ushort16*)(ws + OFF_WFCB);

  hipLaunchKernelGGL(init_kernel, dim3(256), dim3(256), 0, stream, s0, s, bar);
  hipLaunchKernelGGL(hhconst_kernel, dim3(3072), dim3(256), 0, stream,
                     Whh0, Whhr, bih0, bhh0, bihr, bhhr, h0, hhT);
  hipLaunchKernelGGL(wfcswz_kernel, dim3(3072), dim3(256), 0, stream, Wfc, Wfcb);
  for (int sp = 0; sp < 2; ++sp) {
    hipLaunchKernelGGL(gemm_u_kernel, dim3(512, 16), dim3(256), 0, stream,
                       h, Wa + (size_t)sp * HID * FEATD, u);
    hipLaunchKernelGGL(decoder_kernel, dim3(NBLK), dim3(NTHR), 0, stream,
                       h, u, Wih0, Wihr, Wfcb, bfc, c0, hhT, s,
                       x1B4, x2B4, chist4, xhist4, bar,
                       out + (size_t)sp * T_LEN * BATCH * OUTD);
  }
}

// Round 9
// 36419.855 us; speedup vs baseline: 8.3087x; 1.0003x over previous
//
#include <hip/hip_runtime.h>

#define T_LEN 512
#define BATCH 64
#define FEATD 512
#define HID   1024
#define G4H   4096
#define WINR  16
#define WLEN  33
#define OUTD  512
#define CATD  1536
#define NBLK  256
#define NTHR  512

typedef unsigned int uint32;
typedef unsigned long long u64;
typedef unsigned short ushort16;
typedef short s16x8 __attribute__((ext_vector_type(8)));
typedef float f32x4 __attribute__((ext_vector_type(4)));

// ---------------- workspace layout (float offsets) ----------------
static const size_t OFF_U    = 0;
static const size_t OFF_HH   = 33554432;
static const size_t OFF_S    = OFF_HH + 786432;
static const size_t OFF_CB   = OFF_S  + 65536;
static const size_t OFF_X1   = OFF_CB + 16384;
static const size_t OFF_X2   = OFF_X1 + 32768;
static const size_t OFF_CK   = OFF_X2 + 32768;
static const size_t OFF_XK   = OFF_CK + 262144;
static const size_t OFF_BAR  = OFF_XK + 524288;
static const size_t OFF_WFCB = OFF_BAR + 1024;

__device__ __forceinline__ float sigmoidf_(float x) { return 1.0f / (1.0f + expf(-x)); }
__device__ __forceinline__ ushort16 f2bf(float f) {
  uint32 u = __float_as_uint(f);
  uint32 r = u + 0x7FFFu + ((u >> 16) & 1u);   // RNE
  return (ushort16)(r >> 16);
}

// ---- agent-scope (sc1, L2-bypassing) ops for cross-block data ----
__device__ __forceinline__ uint2 aload8(const void* p) {
  u64 v = __hip_atomic_load((const u64*)p, __ATOMIC_RELAXED, __HIP_MEMORY_SCOPE_AGENT);
  uint2 r; r.x = (unsigned)(v & 0xffffffffull); r.y = (unsigned)(v >> 32);
  return r;
}
__device__ __forceinline__ float aload4f(const void* p) {
  return __hip_atomic_load((const float*)p, __ATOMIC_RELAXED, __HIP_MEMORY_SCOPE_AGENT);
}
__device__ __forceinline__ void astore8(void* p, u64 v) {
  __hip_atomic_store((u64*)p, v, __ATOMIC_RELAXED, __HIP_MEMORY_SCOPE_AGENT);
}
__device__ __forceinline__ void astore4f(void* p, float v) {
  __hip_atomic_store((float*)p, v, __ATOMIC_RELAXED, __HIP_MEMORY_SCOPE_AGENT);
}

// -------- monotonic hybrid grid barrier (256 blocks, epoch-counted) --------
// Arrivals spread over 8 group lines (32 members each, 256B apart) to keep
// same-line RMW serialization low. Every 32nd arrival in a group bumps the
// single monotonic gsum; pollers wait gsum >= 8*epoch. Critical path is 2
// chained agent atomics (group add -> gsum add) + one poll observe — one
// L3 round trip shorter than the 3-tier round-8 tree. No resets, no wbl2.
__device__ __forceinline__ void grid_barrier(unsigned* bar, unsigned epoch) {
  __syncthreads();   // drains vmcnt per wave -> sc1 stores are at L3
  if (threadIdx.x == 0) {
    unsigned* cnt  = bar + ((blockIdx.x & 7u) << 6);
    unsigned* gsum = bar + 512;
    unsigned a = __hip_atomic_fetch_add(cnt, 1u, __ATOMIC_RELAXED, __HIP_MEMORY_SCOPE_AGENT);
    if (((a + 1u) & 31u) == 0u)
      __hip_atomic_fetch_add(gsum, 1u, __ATOMIC_RELAXED, __HIP_MEMORY_SCOPE_AGENT);
    const unsigned target = epoch * 8u;
    while ((int)(__hip_atomic_load(gsum, __ATOMIC_RELAXED, __HIP_MEMORY_SCOPE_AGENT) - target) < 0)
      __builtin_amdgcn_s_sleep(2);
  }
  __syncthreads();
}

// ---------------- MFMA LSTM stage ----------------
template<int KSTEPS>
__device__ __forceinline__ void lstm_stage_mfma(
    const ushort16* __restrict__ wl,     // LDS [KSTEPS][64][8]
    const ushort16* __restrict__ actB4,  // global [K/4][64][4]
    const float* __restrict__ hhg,       // [4] preloaded (wv<4)
    float c0v,                           // preloaded (wv<4)
    ushort16* __restrict__ xoutB4,       // next act [H/4][64][4] or null
    ushort16* __restrict__ xhist_slot,   // [H/4][64][4] or null
    float* __restrict__ sOut,            // [B][HID] or null
    float* __restrict__ red,             // LDS [2][4][16][16]
    float* __restrict__ hv_l)            // LDS [4][64]
{
  const int tid  = threadIdx.x;
  const int wv   = tid >> 6;
  const int lane = tid & 63;
  const int nt   = wv & 3;
  const int kh   = wv >> 2;
  const int quad = lane >> 4;
  const int b    = nt * 16 + (lane & 15);
  const int half = KSTEPS / 2;

  f32x4 acc0 = {0.f, 0.f, 0.f, 0.f};
  f32x4 acc1 = {0.f, 0.f, 0.f, 0.f};
  #pragma unroll
  for (int i = 0; i < half; i += 2) {
    const int ks0 = kh * half + i;
    const int ks1 = ks0 + 1;
    s16x8 a0 = *(const s16x8*)(wl + ((size_t)ks0 * 64 + lane) * 8);
    s16x8 a1 = *(const s16x8*)(wl + ((size_t)ks1 * 64 + lane) * 8);
    const int g0 = ks0 * 8 + quad * 2;
    const int g1 = ks1 * 8 + quad * 2;
    uint2 lo0 = aload8(actB4 + ((size_t)g0 * 64 + b) * 4);
    uint2 hi0 = aload8(actB4 + ((size_t)(g0 + 1) * 64 + b) * 4);
    uint2 lo1 = aload8(actB4 + ((size_t)g1 * 64 + b) * 4);
    uint2 hi1 = aload8(actB4 + ((size_t)(g1 + 1) * 64 + b) * 4);
    union { uint4 u; s16x8 v; } b0, b1;
    b0.u = make_uint4(lo0.x, lo0.y, hi0.x, hi0.y);
    b1.u = make_uint4(lo1.x, lo1.y, hi1.x, hi1.y);
    acc0 = __builtin_amdgcn_mfma_f32_16x16x32_bf16(a0, b0.v, acc0, 0, 0, 0);
    acc1 = __builtin_amdgcn_mfma_f32_16x16x32_bf16(a1, b1.v, acc1, 0, 0, 0);
  }
  f32x4 acc = acc0 + acc1;
  // partials: C-layout col=lane&15, row=quad*4+reg
  {
    float* rp = red + (((size_t)(kh * 4 + nt) * 16 + quad * 4) * 16) + (lane & 15);
    rp[0]  = acc[0];
    rp[16] = acc[1];
    rp[32] = acc[2];
    rp[48] = acc[3];
  }
  __syncthreads();
  if (wv < 4) {
    const int jl = wv;
    const int bb = lane;
    const int ntb = bb >> 4, col = bb & 15;
    float g[4];
    #pragma unroll
    for (int gate = 0; gate < 4; ++gate) {
      const int m = gate * 4 + jl;
      g[gate] = red[((size_t)(0 + ntb) * 16 + m) * 16 + col]
              + red[((size_t)(4 + ntb) * 16 + m) * 16 + col]
              + hhg[gate];
    }
    float cn = sigmoidf_(g[1]) * c0v + sigmoidf_(g[0]) * tanhf(g[2]);
    float hv = sigmoidf_(g[3]) * tanhf(cn);
    if (sOut) astore4f(sOut + (size_t)bb * HID + (blockIdx.x << 2) + jl, hv);
    hv_l[jl * 64 + bb] = hv;
  }
  if (xoutB4 || xhist_slot) {
    __syncthreads();
    if (wv == 0) {
      const int bb = lane;
      uint32 lo = (uint32)f2bf(hv_l[0 * 64 + bb]) | ((uint32)f2bf(hv_l[1 * 64 + bb]) << 16);
      uint32 hi = (uint32)f2bf(hv_l[2 * 64 + bb]) | ((uint32)f2bf(hv_l[3 * 64 + bb]) << 16);
      u64 pk = ((u64)hi << 32) | (u64)lo;
      if (xoutB4)     astore8(xoutB4 + ((size_t)blockIdx.x * 64 + bb) * 4, pk);
      if (xhist_slot) astore8(xhist_slot + ((size_t)blockIdx.x * 64 + bb) * 4, pk);
    }
  }
}

// ---------------- FC head on the MFMA pipe ----------------
__device__ __forceinline__ void fc_step_mfma(int tp, int sub,
    const ushort16* __restrict__ ch4,   // [16][F/4][64][4]
    const ushort16* __restrict__ xh4,   // [16][H/4][64][4]
    const ushort16* __restrict__ Wfcb,  // [32][48][64][8]
    const float* __restrict__ bfc,
    float* __restrict__ outp, float* __restrict__ red)
{
  const int tid  = threadIdx.x;
  const int wv   = tid >> 6;
  const int lane = tid & 63;
  const int slot = tp & 15;
  const int ot   = sub >> 1;                 // 0..31
  const int tsel = wv & 1;                   // b-tile within half
  const int kq   = wv >> 1;                  // 0..3 K-quarter
  const int quad = lane >> 4;
  const int b    = ((sub & 1) * 2 + tsel) * 16 + (lane & 15);
  const ushort16* xs = xh4 + (size_t)slot * 65536;   // [256][64][4]
  const ushort16* cs = ch4 + (size_t)slot * 32768;   // [128][64][4]
  const ushort16* wa = Wfcb + ((size_t)ot * 48 + (size_t)kq * 12) * 512;

  f32x4 acc0 = {0.f, 0.f, 0.f, 0.f};
  f32x4 acc1 = {0.f, 0.f, 0.f, 0.f};
  #pragma unroll
  for (int i = 0; i < 12; i += 2) {
    const int ks0 = kq * 12 + i;
    const int ks1 = ks0 + 1;
    s16x8 a0 = *(const s16x8*)(wa + (size_t)i * 512 + (size_t)lane * 8);
    s16x8 a1 = *(const s16x8*)(wa + (size_t)(i + 1) * 512 + (size_t)lane * 8);
    const ushort16* s0p = (ks0 < 32) ? xs : cs;
    const ushort16* s1p = (ks1 < 32) ? xs : cs;
    const int gg0 = ((ks0 < 32) ? ks0 * 8 : (ks0 - 32) * 8) + quad * 2;
    const int gg1 = ((ks1 < 32) ? ks1 * 8 : (ks1 - 32) * 8) + quad * 2;
    uint2 lo0 = aload8(s0p + ((size_t)gg0 * 64 + b) * 4);
    uint2 hi0 = aload8(s0p + ((size_t)(gg0 + 1) * 64 + b) * 4);
    uint2 lo1 = aload8(s1p + ((size_t)gg1 * 64 + b) * 4);
    uint2 hi1 = aload8(s1p + ((size_t)(gg1 + 1) * 64 + b) * 4);
    union { uint4 u; s16x8 v; } b0, b1;
    b0.u = make_uint4(lo0.x, lo0.y, hi0.x, hi0.y);
    b1.u = make_uint4(lo1.x, lo1.y, hi1.x, hi1.y);
    acc0 = __builtin_amdgcn_mfma_f32_16x16x32_bf16(a0, b0.v, acc0, 0, 0, 0);
    acc1 = __builtin_amdgcn_mfma_f32_16x16x32_bf16(a1, b1.v, acc1, 0, 0, 0);
  }
  f32x4 acc = acc0 + acc1;
  {
    float* rp = red + ((size_t)wv * 16 + quad * 4) * 16 + (lane & 15);
    rp[0]  = acc[0];
    rp[16] = acc[1];
    rp[32] = acc[2];
    rp[48] = acc[3];
  }
  __syncthreads();
  {
    const int tl   = tid >> 8;          // b-tile
    const int bcol = (tid >> 4) & 15;
    const int m    = tid & 15;
    float v = bfc[ot * 16 + m];
    #pragma unroll
    for (int k4 = 0; k4 < 4; ++k4)
      v += red[((size_t)(k4 * 2 + tl) * 16 + m) * 16 + bcol];
    const int bo = ((sub & 1) * 2 + tl) * 16 + bcol;
    outp[((size_t)tp * BATCH + bo) * OUTD + ot * 16 + m] = fmaxf(v, 0.f);
  }
}

// ---------------- persistent per-speaker decoder ----------------
__global__ void __launch_bounds__(NTHR)
decoder_kernel(const float* __restrict__ hin, const float* __restrict__ u,
               const float* __restrict__ Wih0, const float* __restrict__ Wihr,
               const ushort16* __restrict__ Wfcb, const float* __restrict__ bfc,
               const float* __restrict__ c0, const float* __restrict__ hhT,
               float* __restrict__ s,
               ushort16* __restrict__ x1B4, ushort16* __restrict__ x2B4,
               ushort16* __restrict__ chist4, ushort16* __restrict__ xhist4,
               unsigned* __restrict__ bar, float* __restrict__ outp)
{
  __shared__ ushort16 wlds[40960];   // 80 KB: B[0,8192) C[8192,24576) D[24576,40960)
  __shared__ float s_l[HID];
  __shared__ float e_l[64];
  __shared__ float a_l[64];
  __shared__ float red[2 * 4 * 16 * 16];
  __shared__ float c_l[FEATD];
  __shared__ float hv_l[4 * 64];

  const int tid  = threadIdx.x;
  const int bid  = blockIdx.x;
  const int wv   = tid >> 6;
  const int lane = tid & 63;

  // ---- one-time: swizzle this block's weight slice into LDS (bf16 A-frags) ----
  for (int r = tid; r < 40960; r += NTHR) {
    int local, ksz; const float* Wsrc;
    if (r < 8192)        { local = r;         ksz = FEATD; Wsrc = Wih0; }
    else if (r < 24576)  { local = r - 8192;  ksz = HID;   Wsrc = Wihr; }
    else                 { local = r - 24576; ksz = HID;   Wsrc = Wihr + (size_t)G4H * HID; }
    const int ks   = local >> 9;
    const int li   = local & 511;
    const int ln   = li >> 3;
    const int jj   = li & 7;
    const int m    = ln & 15;
    const int quad = ln >> 4;
    const int k    = ks * 32 + quad * 8 + jj;
    const int n    = (m >> 2) * HID + (bid << 2) + (m & 3);
    wlds[r] = f2bf(Wsrc[(size_t)n * ksz + k]);
  }

  // ---- one-time: preload gate constants into registers (threads wv<4) ----
  float hh_r[3][4];
  float c0_r[3];
  if (wv < 4) {
    const int j  = (bid << 2) + wv;
    const int bb = lane;
    #pragma unroll
    for (int l = 0; l < 3; ++l) {
      #pragma unroll
      for (int gate = 0; gate < 4; ++gate)
        hh_r[l][gate] = hhT[((size_t)l * G4H + (size_t)gate * HID + j) * 64 + bb];
      c0_r[l] = c0[((size_t)l * BATCH + bb) * HID + j];
    }
  } else {
    #pragma unroll
    for (int l = 0; l < 3; ++l) {
      hh_r[l][0] = hh_r[l][1] = hh_r[l][2] = hh_r[l][3] = 0.f;
      c0_r[l] = 0.f;
    }
  }
  __syncthreads();

  unsigned ep = 0;
  for (int t = 0; t < T_LEN; ++t) {
    const int slot = t & 15;
    // ---- Stage A: attention (blocks 0..63) / FC bursts (blocks 64..255, every 3rd) ----
    if (bid < BATCH) {
      const int b = bid;
      // prefetch next step's new u/hin rows into L2 (consumed by asm sink below)
      float pf0 = 0.f, pf1 = 0.f, pf2 = 0.f;
      {
        const int taun = t + 1 + WINR;
        if (taun < T_LEN) {
          pf0 = u[((size_t)taun * BATCH + b) * HID + tid];
          pf1 = u[((size_t)taun * BATCH + b) * HID + tid + NTHR];
          pf2 = hin[((size_t)taun * BATCH + b) * FEATD + tid];
        }
      }
      // s was produced by other blocks last step -> sc1 loads
      s_l[tid]        = aload4f(s + (size_t)b * HID + tid);
      s_l[tid + NTHR] = aload4f(s + (size_t)b * HID + tid + NTHR);
      __syncthreads();
      for (int w = wv; w < WLEN; w += 8) {
        const int tau = t + w - WINR;
        float e = 0.f;   // zero-padded window -> e=0 participates in softmax
        if (tau >= 0 && tau < T_LEN) {
          const float* up = u + ((size_t)tau * BATCH + b) * HID;
          #pragma unroll
          for (int i = 0; i < 16; ++i) {
            const int hidx = lane + (i << 6);
            e += s_l[hidx] * up[hidx];
          }
          #pragma unroll
          for (int m = 32; m; m >>= 1) e += __shfl_xor(e, m);
        }
        if (lane == 0) e_l[w] = e;
      }
      __syncthreads();
      if (tid < 64) {
        float e = (tid < WLEN) ? e_l[tid] : -1e30f;
        float mx = e;
        #pragma unroll
        for (int m = 32; m; m >>= 1) mx = fmaxf(mx, __shfl_xor(mx, m));
        float p = (tid < WLEN) ? expf(e - mx) : 0.f;
        float sm = p;
        #pragma unroll
        for (int m = 32; m; m >>= 1) sm += __shfl_xor(sm, m);
        if (tid < WLEN) a_l[tid] = p / sm;
      }
      __syncthreads();
      {
        // context: branch-free bounds + quad FMA chains (deep miss pipelining)
        const int w0 = (t < WINR) ? (WINR - t) : 0;
        const int w1 = (T_LEN + WINR - t < WLEN) ? (T_LEN + WINR - t) : WLEN;
        const size_t hstep = (size_t)BATCH * FEATD;
        const float* hp = hin + ((size_t)(t + w0 - WINR) * BATCH + b) * FEATD + tid;
        float c0a = 0.f, c1a = 0.f, c2a = 0.f, c3a = 0.f;
        int w = w0;
        for (; w + 3 < w1; w += 4) {
          c0a = fmaf(a_l[w],     hp[0],         c0a);
          c1a = fmaf(a_l[w + 1], hp[hstep],     c1a);
          c2a = fmaf(a_l[w + 2], hp[2 * hstep], c2a);
          c3a = fmaf(a_l[w + 3], hp[3 * hstep], c3a);
          hp += 4 * hstep;
        }
        for (; w < w1; ++w) { c0a = fmaf(a_l[w], hp[0], c0a); hp += hstep; }
        c_l[tid] = (c0a + c1a) + (c2a + c3a);
      }
      __syncthreads();
      if (tid < 128) {
        // pack 4 consecutive f (one B4 group) -> one 8B sc1 store
        uint32 lo = (uint32)f2bf(c_l[4 * tid + 0]) | ((uint32)f2bf(c_l[4 * tid + 1]) << 16);
        uint32 hi = (uint32)f2bf(c_l[4 * tid + 2]) | ((uint32)f2bf(c_l[4 * tid + 3]) << 16);
        u64 pk = ((u64)hi << 32) | (u64)lo;
        astore8(chist4 + (size_t)slot * 32768 + ((size_t)tid * 64 + b) * 4, pk);
      }
      asm volatile("" :: "v"(pf0), "v"(pf1), "v"(pf2));   // keep prefetches live
    } else if (t >= 3 && t % 3 == 0) {
      const int fb = bid - BATCH;           // 0..191
      const int tp = t - 3 + (fb >> 6);     // 3 timesteps x 64 blocks
      fc_step_mfma(tp, fb & 63, chist4, xhist4, Wfcb, bfc, outp, red);
    }
    grid_barrier(bar, ++ep);
    // ---- Stages B/C/D ----
    lstm_stage_mfma<16>(wlds, chist4 + (size_t)slot * 32768, hh_r[0], c0_r[0],
                        x1B4, nullptr, nullptr, red, hv_l);
    grid_barrier(bar, ++ep);
    lstm_stage_mfma<32>(wlds + 8192, x1B4, hh_r[1], c0_r[1],
                        x2B4, nullptr, nullptr, red, hv_l);
    grid_barrier(bar, ++ep);
    lstm_stage_mfma<32>(wlds + 24576, x2B4, hh_r[2], c0_r[2],
                        nullptr, xhist4 + (size_t)slot * 65536, s, red, hv_l);
    grid_barrier(bar, ++ep);
  }
  // ---- epilogue: FC for tp = 510, 511 on blocks 0..127 ----
  if (bid < 128) {
    const int tp = 510 + (bid >> 6);
    fc_step_mfma(tp, bid & 63, chist4, xhist4, Wfcb, bfc, outp, red);
  }
}

// ---------------- barrier reset (before each decoder launch) ----------------
__global__ void __launch_bounds__(256)
barreset_kernel(unsigned* __restrict__ bar)
{
  for (int i = threadIdx.x; i < 1024; i += 256) bar[i] = 0u;
}

// ---------------- one-time: swizzle Wfc into bf16 MFMA A-frags ----------------
__global__ void __launch_bounds__(256)
wfcswz_kernel(const float* __restrict__ Wfc, ushort16* __restrict__ Wfcb)
{
  const int idx = blockIdx.x * 256 + threadIdx.x;   // 786432 total
  const int ot  = idx / 24576;
  const int r   = idx - ot * 24576;
  const int ks  = r >> 9;
  const int li  = r & 511;
  const int ln  = li >> 3;
  const int j   = li & 7;
  const int k   = ks * 32 + (ln >> 4) * 8 + j;
  const int o   = ot * 16 + (ln & 15);
  Wfcb[idx] = f2bf(Wfc[(size_t)o * CATD + k]);
}

// ---------------- u = h @ Wa_sp^T : [32768,512] x [1024,512]^T (fp32) ----------------
__global__ void __launch_bounds__(256)
gemm_u_kernel(const float* __restrict__ A, const float* __restrict__ Bm,
              float* __restrict__ C)
{
  __shared__ float Al[64 * 68];
  __shared__ float Bl[64 * 68];
  const int tid = threadIdx.x;
  const int m0 = blockIdx.x * 64;
  const int n0 = blockIdx.y * 64;
  const int tx = tid & 15, ty = tid >> 4;
  float acc[4][4] = {};
  for (int kc = 0; kc < 512; kc += 64) {
    #pragma unroll
    for (int p = 0; p < 4; ++p) {
      const int row = p * 16 + (tid >> 4);
      const int kq  = (tid & 15) * 4;
      float4 v = *(const float4*)(A + (size_t)(m0 + row) * 512 + kc + kq);
      Al[(kq + 0) * 68 + row] = v.x;
      Al[(kq + 1) * 68 + row] = v.y;
      Al[(kq + 2) * 68 + row] = v.z;
      Al[(kq + 3) * 68 + row] = v.w;
      float4 w = *(const float4*)(Bm + (size_t)(n0 + row) * 512 + kc + kq);
      Bl[(kq + 0) * 68 + row] = w.x;
      Bl[(kq + 1) * 68 + row] = w.y;
      Bl[(kq + 2) * 68 + row] = w.z;
      Bl[(kq + 3) * 68 + row] = w.w;
    }
    __syncthreads();
    #pragma unroll 8
    for (int k = 0; k < 64; ++k) {
      float4 av = *(const float4*)(&Al[k * 68 + ty * 4]);
      float4 bv = *(const float4*)(&Bl[k * 68 + tx * 4]);
      float aa[4] = {av.x, av.y, av.z, av.w};
      float bb[4] = {bv.x, bv.y, bv.z, bv.w};
      #pragma unroll
      for (int i = 0; i < 4; ++i)
        #pragma unroll
        for (int jj = 0; jj < 4; ++jj)
          acc[i][jj] = fmaf(aa[i], bb[jj], acc[i][jj]);
    }
    __syncthreads();
  }
  #pragma unroll
  for (int i = 0; i < 4; ++i) {
    float4 r = {acc[i][0], acc[i][1], acc[i][2], acc[i][3]};
    *(float4*)(C + (size_t)(m0 + ty * 4 + i) * 1024 + n0 + tx * 4) = r;
  }
}

// ------- hhT[l][n][b] = h0[l,b,:] . Whh_l[n,:] + bih_l[n] + bhh_l[n] -------
__global__ void __launch_bounds__(256)
hhconst_kernel(const float* __restrict__ Whh0, const float* __restrict__ Whr,
               const float* __restrict__ bih0, const float* __restrict__ bhh0,
               const float* __restrict__ bihr, const float* __restrict__ bhhr,
               const float* __restrict__ h0, float* __restrict__ hh)
{
  const int idx = blockIdx.x * 256 + threadIdx.x;   // 786432 total
  const int b = idx & 63;
  const int n = (idx >> 6) & 4095;
  const int l = idx >> 18;
  const float* W = (l == 0) ? (Whh0 + (size_t)n * HID)
                            : (Whr + ((size_t)(l - 1) * G4H + n) * HID);
  float acc = ((l == 0) ? bih0[n] : bihr[(l - 1) * G4H + n])
            + ((l == 0) ? bhh0[n] : bhhr[(l - 1) * G4H + n]);
  const float* hr = h0 + ((size_t)l * BATCH + b) * HID;
  #pragma unroll 2
  for (int k = 0; k < HID; k += 4) {
    float4 a4 = *(const float4*)(hr + k);
    float4 w4 = *(const float4*)(W + k);
    acc += a4.x * w4.x + a4.y * w4.y + a4.z * w4.z + a4.w * w4.w;
  }
  hh[idx] = acc;    // (l*G4H + n)*64 + b  -> k-major, coalesced
}

__global__ void __launch_bounds__(256)
init_kernel(const float* __restrict__ s0, float* __restrict__ s, unsigned* __restrict__ bar)
{
  const int gid = blockIdx.x * 256 + threadIdx.x;
  if (gid < BATCH * HID) s[gid] = s0[gid];
  if (blockIdx.x == 0)
    for (int i = threadIdx.x; i < 1024; i += 256) bar[i] = 0u;
}

extern "C" void kernel_launch(void* const* d_in, const int* in_sizes, int n_in,
                              void* d_out, int out_size, void* d_ws, size_t ws_size,
                              hipStream_t stream) {
  (void)in_sizes; (void)n_in; (void)out_size; (void)ws_size;
  const float* h    = (const float*)d_in[0];
  const float* Wa   = (const float*)d_in[1];
  const float* Wih0 = (const float*)d_in[2];
  const float* Whh0 = (const float*)d_in[3];
  const float* bih0 = (const float*)d_in[4];
  const float* bhh0 = (const float*)d_in[5];
  const float* Wihr = (const float*)d_in[6];
  const float* Whhr = (const float*)d_in[7];
  const float* bihr = (const float*)d_in[8];
  const float* bhhr = (const float*)d_in[9];
  const float* Wfc  = (const float*)d_in[10];
  const float* bfc  = (const float*)d_in[11];
  const float* s0   = (const float*)d_in[12];
  const float* h0   = (const float*)d_in[13];
  const float* c0   = (const float*)d_in[14];
  float* out = (float*)d_out;
  float* ws  = (float*)d_ws;

  float* u         = ws + OFF_U;
  float* hhT       = ws + OFF_HH;
  float* s         = ws + OFF_S;
  ushort16* x1B4   = (ushort16*)(ws + OFF_X1);
  ushort16* x2B4   = (ushort16*)(ws + OFF_X2);
  ushort16* chist4 = (ushort16*)(ws + OFF_CK);
  ushort16* xhist4 = (ushort16*)(ws + OFF_XK);
  unsigned* bar    = (unsigned*)(ws + OFF_BAR);
  ushort16* Wfcb   = (ushort16*)(ws + OFF_WFCB);

  hipLaunchKernelGGL(init_kernel, dim3(256), dim3(256), 0, stream, s0, s, bar);
  hipLaunchKernelGGL(hhconst_kernel, dim3(3072), dim3(256), 0, stream,
                     Whh0, Whhr, bih0, bhh0, bihr, bhhr, h0, hhT);
  hipLaunchKernelGGL(wfcswz_kernel, dim3(3072), dim3(256), 0, stream, Wfc, Wfcb);
  for (int sp = 0; sp < 2; ++sp) {
    hipLaunchKernelGGL(gemm_u_kernel, dim3(512, 16), dim3(256), 0, stream,
                       h, Wa + (size_t)sp * HID * FEATD, u);
    hipLaunchKernelGGL(barreset_kernel, dim3(1), dim3(256), 0, stream, bar);
    hipLaunchKernelGGL(decoder_kernel, dim3(NBLK), dim3(NTHR), 0, stream,
                       h, u, Wih0, Wihr, Wfcb, bfc, c0, hhT, s,
                       x1B4, x2B4, chist4, xhist4, bar,
                       out + (size_t)sp * T_LEN * BATCH * OUTD);
  }
}

// Round 11
// 34996.848 us; speedup vs baseline: 8.6465x; 1.0407x over previous
//
#include <hip/hip_runtime.h>

#define T_LEN 512
#define BATCH 64
#define FEATD 512
#define HID   1024
#define G4H   4096
#define WINR  16
#define WLEN  33
#define OUTD  512
#define CATD  1536
#define NBLK  256
#define NTHR  512

typedef unsigned int uint32;
typedef unsigned long long u64;
typedef unsigned short ushort16;
typedef short s16x8 __attribute__((ext_vector_type(8)));
typedef float f32x4 __attribute__((ext_vector_type(4)));

// ---------------- workspace layout (float offsets) ----------------
static const size_t OFF_U    = 0;
static const size_t OFF_HH   = 33554432;
static const size_t OFF_S    = OFF_HH + 786432;
static const size_t OFF_CB   = OFF_S  + 65536;
static const size_t OFF_X1   = OFF_CB + 16384;
static const size_t OFF_X2   = OFF_X1 + 32768;
static const size_t OFF_CK   = OFF_X2 + 32768;
static const size_t OFF_XK   = OFF_CK + 262144;
static const size_t OFF_BAR  = OFF_XK + 524288;   // 2048 u32
static const size_t OFF_WFCB = OFF_BAR + 2048;

__device__ __forceinline__ float sigmoidf_(float x) { return 1.0f / (1.0f + expf(-x)); }
__device__ __forceinline__ ushort16 f2bf(float f) {
  uint32 u = __float_as_uint(f);
  uint32 r = u + 0x7FFFu + ((u >> 16) & 1u);   // RNE
  return (ushort16)(r >> 16);
}

// ---- agent-scope (sc1, L2-bypassing) ops for cross-block data ----
__device__ __forceinline__ uint2 aload8(const void* p) {
  u64 v = __hip_atomic_load((const u64*)p, __ATOMIC_RELAXED, __HIP_MEMORY_SCOPE_AGENT);
  uint2 r; r.x = (unsigned)(v & 0xffffffffull); r.y = (unsigned)(v >> 32);
  return r;
}
__device__ __forceinline__ float aload4f(const void* p) {
  return __hip_atomic_load((const float*)p, __ATOMIC_RELAXED, __HIP_MEMORY_SCOPE_AGENT);
}
__device__ __forceinline__ void astore8(void* p, u64 v) {
  __hip_atomic_store((u64*)p, v, __ATOMIC_RELAXED, __HIP_MEMORY_SCOPE_AGENT);
}
__device__ __forceinline__ void astore4f(void* p, float v) {
  __hip_atomic_store((float*)p, v, __ATOMIC_RELAXED, __HIP_MEMORY_SCOPE_AGENT);
}

// ------ broadcast-release grid barrier (256 blocks, epoch-counted) ------
// Arrivals: 8 spread group lines (32 members each). Group's 32nd arrival
// bumps monotonic gsum. The incrementer whose add completes the epoch
// (returns 8*epoch-1) becomes the releaser and fans the epoch out to 16
// release slots 128B apart. Each block polls only rel[bid&15] -> 16
// pollers/line (was 256 on one line), and arrival lines are never polled.
// Visibility: vmcnt(0) at __syncthreads puts all sc1 stores at L3 before
// the arrival RMW; releaser observed all arrivals => all data at L3.
__device__ __forceinline__ void grid_barrier(unsigned* bar, unsigned epoch) {
  __syncthreads();   // drains vmcnt per wave -> sc1 stores are at L3
  if (threadIdx.x == 0) {
    unsigned* cnt  = bar + ((blockIdx.x & 7u) << 6);   // 256B apart
    unsigned* gsum = bar + 512;
    unsigned* rel  = bar + 576;                        // 16 slots, 32 u32 (128B) apart
    unsigned a = __hip_atomic_fetch_add(cnt, 1u, __ATOMIC_RELAXED, __HIP_MEMORY_SCOPE_AGENT);
    if (((a + 1u) & 31u) == 0u) {
      unsigned og = __hip_atomic_fetch_add(gsum, 1u, __ATOMIC_RELAXED, __HIP_MEMORY_SCOPE_AGENT);
      if (og + 1u == epoch * 8u) {
        #pragma unroll
        for (int i = 0; i < 16; ++i)
          __hip_atomic_store(rel + i * 32, epoch, __ATOMIC_RELAXED, __HIP_MEMORY_SCOPE_AGENT);
      }
    }
    unsigned* myrel = rel + (blockIdx.x & 15u) * 32;
    while ((int)(__hip_atomic_load(myrel, __ATOMIC_RELAXED, __HIP_MEMORY_SCOPE_AGENT) - epoch) < 0)
      __builtin_amdgcn_s_sleep(1);
  }
  __syncthreads();
}

// ---------------- MFMA LSTM stage ----------------
// Gate tail: thread (wv<4, lane) owns (bb = wv*16 + (lane>>2), jl = lane&3).
// hv packing via 2 shfl_xor (no LDS staging, no extra __syncthreads).
template<int KSTEPS>
__device__ __forceinline__ void lstm_stage_mfma(
    const ushort16* __restrict__ wl,     // LDS [KSTEPS][64][8]
    const ushort16* __restrict__ actB4,  // global [K/4][64][4]
    const float* __restrict__ hhg,       // [4] preloaded (wv<4)
    float c0v,                           // preloaded (wv<4)
    ushort16* __restrict__ xoutB4,       // next act [H/4][64][4] or null
    ushort16* __restrict__ xhist_slot,   // [H/4][64][4] or null
    float* __restrict__ sOut,            // [B][HID] or null
    float* __restrict__ red)             // LDS [2][4][16][16]
{
  const int tid  = threadIdx.x;
  const int wv   = tid >> 6;
  const int lane = tid & 63;
  const int nt   = wv & 3;
  const int kh   = wv >> 2;
  const int quad = lane >> 4;
  const int b    = nt * 16 + (lane & 15);
  const int half = KSTEPS / 2;

  f32x4 acc0 = {0.f, 0.f, 0.f, 0.f};
  f32x4 acc1 = {0.f, 0.f, 0.f, 0.f};
  #pragma unroll
  for (int i = 0; i < half; i += 2) {
    const int ks0 = kh * half + i;
    const int ks1 = ks0 + 1;
    s16x8 a0 = *(const s16x8*)(wl + ((size_t)ks0 * 64 + lane) * 8);
    s16x8 a1 = *(const s16x8*)(wl + ((size_t)ks1 * 64 + lane) * 8);
    const int g0 = ks0 * 8 + quad * 2;
    const int g1 = ks1 * 8 + quad * 2;
    uint2 lo0 = aload8(actB4 + ((size_t)g0 * 64 + b) * 4);
    uint2 hi0 = aload8(actB4 + ((size_t)(g0 + 1) * 64 + b) * 4);
    uint2 lo1 = aload8(actB4 + ((size_t)g1 * 64 + b) * 4);
    uint2 hi1 = aload8(actB4 + ((size_t)(g1 + 1) * 64 + b) * 4);
    union { uint4 u; s16x8 v; } b0, b1;
    b0.u = make_uint4(lo0.x, lo0.y, hi0.x, hi0.y);
    b1.u = make_uint4(lo1.x, lo1.y, hi1.x, hi1.y);
    acc0 = __builtin_amdgcn_mfma_f32_16x16x32_bf16(a0, b0.v, acc0, 0, 0, 0);
    acc1 = __builtin_amdgcn_mfma_f32_16x16x32_bf16(a1, b1.v, acc1, 0, 0, 0);
  }
  f32x4 acc = acc0 + acc1;
  // partials: C-layout col=lane&15, row=quad*4+reg
  {
    float* rp = red + (((size_t)(kh * 4 + nt) * 16 + quad * 4) * 16) + (lane & 15);
    rp[0]  = acc[0];
    rp[16] = acc[1];
    rp[32] = acc[2];
    rp[48] = acc[3];
  }
  __syncthreads();
  if (wv < 4) {
    const int jl  = lane & 3;
    const int bb  = wv * 16 + (lane >> 2);
    const int ntb = bb >> 4;          // == wv
    const int col = bb & 15;
    float g[4];
    #pragma unroll
    for (int gate = 0; gate < 4; ++gate) {
      const int m = gate * 4 + jl;
      g[gate] = red[((size_t)(0 + ntb) * 16 + m) * 16 + col]
              + red[((size_t)(4 + ntb) * 16 + m) * 16 + col]
              + hhg[gate];
    }
    float cn = sigmoidf_(g[1]) * c0v + sigmoidf_(g[0]) * tanhf(g[2]);
    float hv = sigmoidf_(g[3]) * tanhf(cn);
    if (sOut) astore4f(sOut + (size_t)bb * HID + (blockIdx.x << 2) + jl, hv);
    if (xoutB4 || xhist_slot) {
      // pack hv of jl=0..3 (same bb, 4-lane group) into one u64 via shfl
      uint32 my = ((uint32)f2bf(hv)) << ((jl & 1) * 16);
      uint32 pair = my | (uint32)__shfl_xor((int)my, 1);        // (hv0|hv1<<16) or (hv2|hv3<<16)
      uint32 other = (uint32)__shfl_xor((int)pair, 2);
      if (jl == 0) {
        u64 pk = ((u64)other << 32) | (u64)pair;
        if (xoutB4)     astore8(xoutB4 + ((size_t)blockIdx.x * 64 + bb) * 4, pk);
        if (xhist_slot) astore8(xhist_slot + ((size_t)blockIdx.x * 64 + bb) * 4, pk);
      }
    }
  }
}

// ---------------- FC head on the MFMA pipe ----------------
__device__ __forceinline__ void fc_step_mfma(int tp, int sub,
    const ushort16* __restrict__ ch4,   // [16][F/4][64][4]
    const ushort16* __restrict__ xh4,   // [16][H/4][64][4]
    const ushort16* __restrict__ Wfcb,  // [32][48][64][8]
    const float* __restrict__ bfc,
    float* __restrict__ outp, float* __restrict__ red)
{
  const int tid  = threadIdx.x;
  const int wv   = tid >> 6;
  const int lane = tid & 63;
  const int slot = tp & 15;
  const int ot   = sub >> 1;                 // 0..31
  const int tsel = wv & 1;                   // b-tile within half
  const int kq   = wv >> 1;                  // 0..3 K-quarter
  const int quad = lane >> 4;
  const int b    = ((sub & 1) * 2 + tsel) * 16 + (lane & 15);
  const ushort16* xs = xh4 + (size_t)slot * 65536;   // [256][64][4]
  const ushort16* cs = ch4 + (size_t)slot * 32768;   // [128][64][4]
  const ushort16* wa = Wfcb + ((size_t)ot * 48 + (size_t)kq * 12) * 512;

  f32x4 acc0 = {0.f, 0.f, 0.f, 0.f};
  f32x4 acc1 = {0.f, 0.f, 0.f, 0.f};
  #pragma unroll
  for (int i = 0; i < 12; i += 2) {
    const int ks0 = kq * 12 + i;
    const int ks1 = ks0 + 1;
    s16x8 a0 = *(const s16x8*)(wa + (size_t)i * 512 + (size_t)lane * 8);
    s16x8 a1 = *(const s16x8*)(wa + (size_t)(i + 1) * 512 + (size_t)lane * 8);
    const ushort16* s0p = (ks0 < 32) ? xs : cs;
    const ushort16* s1p = (ks1 < 32) ? xs : cs;
    const int gg0 = ((ks0 < 32) ? ks0 * 8 : (ks0 - 32) * 8) + quad * 2;
    const int gg1 = ((ks1 < 32) ? ks1 * 8 : (ks1 - 32) * 8) + quad * 2;
    uint2 lo0 = aload8(s0p + ((size_t)gg0 * 64 + b) * 4);
    uint2 hi0 = aload8(s0p + ((size_t)(gg0 + 1) * 64 + b) * 4);
    uint2 lo1 = aload8(s1p + ((size_t)gg1 * 64 + b) * 4);
    uint2 hi1 = aload8(s1p + ((size_t)(gg1 + 1) * 64 + b) * 4);
    union { uint4 u; s16x8 v; } b0, b1;
    b0.u = make_uint4(lo0.x, lo0.y, hi0.x, hi0.y);
    b1.u = make_uint4(lo1.x, lo1.y, hi1.x, hi1.y);
    acc0 = __builtin_amdgcn_mfma_f32_16x16x32_bf16(a0, b0.v, acc0, 0, 0, 0);
    acc1 = __builtin_amdgcn_mfma_f32_16x16x32_bf16(a1, b1.v, acc1, 0, 0, 0);
  }
  f32x4 acc = acc0 + acc1;
  {
    float* rp = red + ((size_t)wv * 16 + quad * 4) * 16 + (lane & 15);
    rp[0]  = acc[0];
    rp[16] = acc[1];
    rp[32] = acc[2];
    rp[48] = acc[3];
  }
  __syncthreads();
  {
    const int tl   = tid >> 8;          // b-tile
    const int bcol = (tid >> 4) & 15;
    const int m    = tid & 15;
    float v = bfc[ot * 16 + m];
    #pragma unroll
    for (int k4 = 0; k4 < 4; ++k4)
      v += red[((size_t)(k4 * 2 + tl) * 16 + m) * 16 + bcol];
    const int bo = ((sub & 1) * 2 + tl) * 16 + bcol;
    outp[((size_t)tp * BATCH + bo) * OUTD + ot * 16 + m] = fmaxf(v, 0.f);
  }
}

// ---------------- persistent per-speaker decoder ----------------
__global__ void __launch_bounds__(NTHR)
decoder_kernel(const float* __restrict__ hin, const float* __restrict__ u,
               const float* __restrict__ Wih0, const float* __restrict__ Wihr,
               const ushort16* __restrict__ Wfcb, const float* __restrict__ bfc,
               const float* __restrict__ c0, const float* __restrict__ hhT,
               float* __restrict__ s,
               ushort16* __restrict__ x1B4, ushort16* __restrict__ x2B4,
               ushort16* __restrict__ chist4, ushort16* __restrict__ xhist4,
               unsigned* __restrict__ bar, float* __restrict__ outp)
{
  __shared__ ushort16 wlds[40960];   // 80 KB: B[0,8192) C[8192,24576) D[24576,40960)
  __shared__ float s_l[HID];
  __shared__ float e_l[64];
  __shared__ float a_l[64];
  __shared__ float red[2 * 4 * 16 * 16];
  __shared__ float c_l[FEATD];

  const int tid  = threadIdx.x;
  const int bid  = blockIdx.x;
  const int wv   = tid >> 6;
  const int lane = tid & 63;

  // ---- one-time: swizzle this block's weight slice into LDS (bf16 A-frags) ----
  for (int r = tid; r < 40960; r += NTHR) {
    int local, ksz; const float* Wsrc;
    if (r < 8192)        { local = r;         ksz = FEATD; Wsrc = Wih0; }
    else if (r < 24576)  { local = r - 8192;  ksz = HID;   Wsrc = Wihr; }
    else                 { local = r - 24576; ksz = HID;   Wsrc = Wihr + (size_t)G4H * HID; }
    const int ks   = local >> 9;
    const int li   = local & 511;
    const int ln   = li >> 3;
    const int jj   = li & 7;
    const int m    = ln & 15;
    const int quad = ln >> 4;
    const int k    = ks * 32 + quad * 8 + jj;
    const int n    = (m >> 2) * HID + (bid << 2) + (m & 3);
    wlds[r] = f2bf(Wsrc[(size_t)n * ksz + k]);
  }

  // ---- one-time: preload gate constants (thread owns bb = wv*16+(lane>>2), jl = lane&3) ----
  float hh_r[3][4];
  float c0_r[3];
  if (wv < 4) {
    const int jl = lane & 3;
    const int bb = wv * 16 + (lane >> 2);
    const int j  = (bid << 2) + jl;
    #pragma unroll
    for (int l = 0; l < 3; ++l) {
      #pragma unroll
      for (int gate = 0; gate < 4; ++gate)
        hh_r[l][gate] = hhT[((size_t)l * G4H + (size_t)gate * HID + j) * 64 + bb];
      c0_r[l] = c0[((size_t)l * BATCH + bb) * HID + j];
    }
  } else {
    #pragma unroll
    for (int l = 0; l < 3; ++l) {
      hh_r[l][0] = hh_r[l][1] = hh_r[l][2] = hh_r[l][3] = 0.f;
      c0_r[l] = 0.f;
    }
  }
  __syncthreads();

  unsigned ep = 0;
  for (int t = 0; t < T_LEN; ++t) {
    const int slot = t & 15;
    // ---- Stage A: attention (blocks 0..63) / FC bursts (blocks 64..255, every 3rd) ----
    if (bid < BATCH) {
      const int b = bid;
      // prefetch next step's new u/hin rows into L2 (consumed by asm sink below)
      float pf0 = 0.f, pf1 = 0.f, pf2 = 0.f;
      {
        const int taun = t + 1 + WINR;
        if (taun < T_LEN) {
          pf0 = u[((size_t)taun * BATCH + b) * HID + tid];
          pf1 = u[((size_t)taun * BATCH + b) * HID + tid + NTHR];
          pf2 = hin[((size_t)taun * BATCH + b) * FEATD + tid];
        }
      }
      // s was produced by other blocks last step -> sc1 loads
      s_l[tid]        = aload4f(s + (size_t)b * HID + tid);
      s_l[tid + NTHR] = aload4f(s + (size_t)b * HID + tid + NTHR);
      __syncthreads();
      for (int w = wv; w < WLEN; w += 8) {
        const int tau = t + w - WINR;
        float e = 0.f;   // zero-padded window -> e=0 participates in softmax
        if (tau >= 0 && tau < T_LEN) {
          const float* up = u + ((size_t)tau * BATCH + b) * HID;
          #pragma unroll
          for (int i = 0; i < 16; ++i) {
            const int hidx = lane + (i << 6);
            e += s_l[hidx] * up[hidx];
          }
          #pragma unroll
          for (int m = 32; m; m >>= 1) e += __shfl_xor(e, m);
        }
        if (lane == 0) e_l[w] = e;
      }
      __syncthreads();
      if (tid < 64) {
        float e = (tid < WLEN) ? e_l[tid] : -1e30f;
        float mx = e;
        #pragma unroll
        for (int m = 32; m; m >>= 1) mx = fmaxf(mx, __shfl_xor(mx, m));
        float p = (tid < WLEN) ? expf(e - mx) : 0.f;
        float sm = p;
        #pragma unroll
        for (int m = 32; m; m >>= 1) sm += __shfl_xor(sm, m);
        if (tid < WLEN) a_l[tid] = p / sm;
      }
      __syncthreads();
      {
        // context: branch-free bounds + quad FMA chains (deep miss pipelining)
        const int w0 = (t < WINR) ? (WINR - t) : 0;
        const int w1 = (T_LEN + WINR - t < WLEN) ? (T_LEN + WINR - t) : WLEN;
        const size_t hstep = (size_t)BATCH * FEATD;
        const float* hp = hin + ((size_t)(t + w0 - WINR) * BATCH + b) * FEATD + tid;
        float c0a = 0.f, c1a = 0.f, c2a = 0.f, c3a = 0.f;
        int w = w0;
        for (; w + 3 < w1; w += 4) {
          c0a = fmaf(a_l[w],     hp[0],         c0a);
          c1a = fmaf(a_l[w + 1], hp[hstep],     c1a);
          c2a = fmaf(a_l[w + 2], hp[2 * hstep], c2a);
          c3a = fmaf(a_l[w + 3], hp[3 * hstep], c3a);
          hp += 4 * hstep;
        }
        for (; w < w1; ++w) { c0a = fmaf(a_l[w], hp[0], c0a); hp += hstep; }
        c_l[tid] = (c0a + c1a) + (c2a + c3a);
      }
      __syncthreads();
      if (tid < 128) {
        // pack 4 consecutive f (one B4 group) -> one 8B sc1 store
        uint32 lo = (uint32)f2bf(c_l[4 * tid + 0]) | ((uint32)f2bf(c_l[4 * tid + 1]) << 16);
        uint32 hi = (uint32)f2bf(c_l[4 * tid + 2]) | ((uint32)f2bf(c_l[4 * tid + 3]) << 16);
        u64 pk = ((u64)hi << 32) | (u64)lo;
        astore8(chist4 + (size_t)slot * 32768 + ((size_t)tid * 64 + b) * 4, pk);
      }
      asm volatile("" :: "v"(pf0), "v"(pf1), "v"(pf2));   // keep prefetches live
    } else if (t >= 3 && t % 3 == 0) {
      const int fb = bid - BATCH;           // 0..191
      const int tp = t - 3 + (fb >> 6);     // 3 timesteps x 64 blocks
      fc_step_mfma(tp, fb & 63, chist4, xhist4, Wfcb, bfc, outp, red);
    }
    grid_barrier(bar, ++ep);
    // ---- Stages B/C/D ----
    lstm_stage_mfma<16>(wlds, chist4 + (size_t)slot * 32768, hh_r[0], c0_r[0],
                        x1B4, nullptr, nullptr, red);
    grid_barrier(bar, ++ep);
    lstm_stage_mfma<32>(wlds + 8192, x1B4, hh_r[1], c0_r[1],
                        x2B4, nullptr, nullptr, red);
    grid_barrier(bar, ++ep);
    lstm_stage_mfma<32>(wlds + 24576, x2B4, hh_r[2], c0_r[2],
                        nullptr, xhist4 + (size_t)slot * 65536, s, red);
    grid_barrier(bar, ++ep);
  }
  // ---- epilogue: FC for tp = 510, 511 on blocks 0..127 ----
  if (bid < 128) {
    const int tp = 510 + (bid >> 6);
    fc_step_mfma(tp, bid & 63, chist4, xhist4, Wfcb, bfc, outp, red);
  }
}

// ---------------- barrier reset (before each decoder launch) ----------------
__global__ void __launch_bounds__(256)
barreset_kernel(unsigned* __restrict__ bar)
{
  for (int i = threadIdx.x; i < 2048; i += 256) bar[i] = 0u;
}

// ---------------- one-time: swizzle Wfc into bf16 MFMA A-frags ----------------
__global__ void __launch_bounds__(256)
wfcswz_kernel(const float* __restrict__ Wfc, ushort16* __restrict__ Wfcb)
{
  const int idx = blockIdx.x * 256 + threadIdx.x;   // 786432 total
  const int ot  = idx / 24576;
  const int r   = idx - ot * 24576;
  const int ks  = r >> 9;
  const int li  = r & 511;
  const int ln  = li >> 3;
  const int j   = li & 7;
  const int k   = ks * 32 + (ln >> 4) * 8 + j;
  const int o   = ot * 16 + (ln & 15);
  Wfcb[idx] = f2bf(Wfc[(size_t)o * CATD + k]);
}

// ---------------- u = h @ Wa_sp^T : [32768,512] x [1024,512]^T (fp32) ----------------
__global__ void __launch_bounds__(256)
gemm_u_kernel(const float* __restrict__ A, const float* __restrict__ Bm,
              float* __restrict__ C)
{
  __shared__ float Al[64 * 68];
  __shared__ float Bl[64 * 68];
  const int tid = threadIdx.x;
  const int m0 = blockIdx.x * 64;
  const int n0 = blockIdx.y * 64;
  const int tx = tid & 15, ty = tid >> 4;
  float acc[4][4] = {};
  for (int kc = 0; kc < 512; kc += 64) {
    #pragma unroll
    for (int p = 0; p < 4; ++p) {
      const int row = p * 16 + (tid >> 4);
      const int kq  = (tid & 15) * 4;
      float4 v = *(const float4*)(A + (size_t)(m0 + row) * 512 + kc + kq);
      Al[(kq + 0) * 68 + row] = v.x;
      Al[(kq + 1) * 68 + row] = v.y;
      Al[(kq + 2) * 68 + row] = v.z;
      Al[(kq + 3) * 68 + row] = v.w;
      float4 w = *(const float4*)(Bm + (size_t)(n0 + row) * 512 + kc + kq);
      Bl[(kq + 0) * 68 + row] = w.x;
      Bl[(kq + 1) * 68 + row] = w.y;
      Bl[(kq + 2) * 68 + row] = w.z;
      Bl[(kq + 3) * 68 + row] = w.w;
    }
    __syncthreads();
    #pragma unroll 8
    for (int k = 0; k < 64; ++k) {
      float4 av = *(const float4*)(&Al[k * 68 + ty * 4]);
      float4 bv = *(const float4*)(&Bl[k * 68 + tx * 4]);
      float aa[4] = {av.x, av.y, av.z, av.w};
      float bb[4] = {bv.x, bv.y, bv.z, bv.w};
      #pragma unroll
      for (int i = 0; i < 4; ++i)
        #pragma unroll
        for (int jj = 0; jj < 4; ++jj)
          acc[i][jj] = fmaf(aa[i], bb[jj], acc[i][jj]);
    }
    __syncthreads();
  }
  #pragma unroll
  for (int i = 0; i < 4; ++i) {
    float4 r = {acc[i][0], acc[i][1], acc[i][2], acc[i][3]};
    *(float4*)(C + (size_t)(m0 + ty * 4 + i) * 1024 + n0 + tx * 4) = r;
  }
}

// ------- hhT[l][n][b] = h0[l,b,:] . Whh_l[n,:] + bih_l[n] + bhh_l[n] -------
__global__ void __launch_bounds__(256)
hhconst_kernel(const float* __restrict__ Whh0, const float* __restrict__ Whr,
               const float* __restrict__ bih0, const float* __restrict__ bhh0,
               const float* __restrict__ bihr, const float* __restrict__ bhhr,
               const float* __restrict__ h0, float* __restrict__ hh)
{
  const int idx = blockIdx.x * 256 + threadIdx.x;   // 786432 total
  const int b = idx & 63;
  const int n = (idx >> 6) & 4095;
  const int l = idx >> 18;
  const float* W = (l == 0) ? (Whh0 + (size_t)n * HID)
                            : (Whr + ((size_t)(l - 1) * G4H + n) * HID);
  float acc = ((l == 0) ? bih0[n] : bihr[(l - 1) * G4H + n])
            + ((l == 0) ? bhh0[n] : bhhr[(l - 1) * G4H + n]);
  const float* hr = h0 + ((size_t)l * BATCH + b) * HID;
  #pragma unroll 2
  for (int k = 0; k < HID; k += 4) {
    float4 a4 = *(const float4*)(hr + k);
    float4 w4 = *(const float4*)(W + k);
    acc += a4.x * w4.x + a4.y * w4.y + a4.z * w4.z + a4.w * w4.w;
  }
  hh[idx] = acc;    // (l*G4H + n)*64 + b  -> k-major, coalesced
}

__global__ void __launch_bounds__(256)
init_kernel(const float* __restrict__ s0, float* __restrict__ s, unsigned* __restrict__ bar)
{
  const int gid = blockIdx.x * 256 + threadIdx.x;
  if (gid < BATCH * HID) s[gid] = s0[gid];
  if (blockIdx.x == 0)
    for (int i = threadIdx.x; i < 2048; i += 256) bar[i] = 0u;
}

extern "C" void kernel_launch(void* const* d_in, const int* in_sizes, int n_in,
                              void* d_out, int out_size, void* d_ws, size_t ws_size,
                              hipStream_t stream) {
  (void)in_sizes; (void)n_in; (void)out_size; (void)ws_size;
  const float* h    = (const float*)d_in[0];
  const float* Wa   = (const float*)d_in[1];
  const float* Wih0 = (const float*)d_in[2];
  const float* Whh0 = (const float*)d_in[3];
  const float* bih0 = (const float*)d_in[4];
  const float* bhh0 = (const float*)d_in[5];
  const float* Wihr = (const float*)d_in[6];
  const float* Whhr = (const float*)d_in[7];
  const float* bihr = (const float*)d_in[8];
  const float* bhhr = (const float*)d_in[9];
  const float* Wfc  = (const float*)d_in[10];
  const float* bfc  = (const float*)d_in[11];
  const float* s0   = (const float*)d_in[12];
  const float* h0   = (const float*)d_in[13];
  const float* c0   = (const float*)d_in[14];
  float* out = (float*)d_out;
  float* ws  = (float*)d_ws;

  float* u         = ws + OFF_U;
  float* hhT       = ws + OFF_HH;
  float* s         = ws + OFF_S;
  ushort16* x1B4   = (ushort16*)(ws + OFF_X1);
  ushort16* x2B4   = (ushort16*)(ws + OFF_X2);
  ushort16* chist4 = (ushort16*)(ws + OFF_CK);
  ushort16* xhist4 = (ushort16*)(ws + OFF_XK);
  unsigned* bar    = (unsigned*)(ws + OFF_BAR);
  ushort16* Wfcb   = (ushort16*)(ws + OFF_WFCB);

  hipLaunchKernelGGL(init_kernel, dim3(256), dim3(256), 0, stream, s0, s, bar);
  hipLaunchKernelGGL(hhconst_kernel, dim3(3072), dim3(256), 0, stream,
                     Whh0, Whhr, bih0, bhh0, bihr, bhhr, h0, hhT);
  hipLaunchKernelGGL(wfcswz_kernel, dim3(3072), dim3(256), 0, stream, Wfc, Wfcb);
  for (int sp = 0; sp < 2; ++sp) {
    hipLaunchKernelGGL(gemm_u_kernel, dim3(512, 16), dim3(256), 0, stream,
                       h, Wa + (size_t)sp * HID * FEATD, u);
    hipLaunchKernelGGL(barreset_kernel, dim3(1), dim3(256), 0, stream, bar);
    hipLaunchKernelGGL(decoder_kernel, dim3(NBLK), dim3(NTHR), 0, stream,
                       h, u, Wih0, Wihr, Wfcb, bfc, c0, hhT, s,
                       x1B4, x2B4, chist4, xhist4, bar,
                       out + (size_t)sp * T_LEN * BATCH * OUTD);
  }
}